// Round 3
// baseline (493.749 us; speedup 1.0000x reference)
//
#include <hip/hip_runtime.h>

#define B_ 128
#define L_ 200
#define D_ 128
#define M_ 64
#define PP 16      // positions per block (K1/K3)
#define SD 132     // padded LDS stride for D=128 rows (132 = 33 float4s)

// ---------- helpers ----------
__device__ __forceinline__ float fast_sigmoid(float x) {
    return 1.f / (1.f + __expf(-x));
}

__device__ __forceinline__ float fast_tanh(float x) {
    float xc = fminf(fmaxf(x, -15.f), 15.f);
    float e = __expf(2.f * xc);
    return (e - 1.f) / (e + 1.f);
}

// ---------- workspace layout (float offsets) ----------
#define F_WQ   0u          // 1638400  w     (B*L, 64)
#define F_EQ   1638400u    // 3276800  e     (B*L, 128)
#define F_AQ   4915200u    // 3276800  a     (B*L, 128)
#define F_FKQ  8192000u    // 3276800  fk    (B*L, 128)
#define F_RD   11468800u   // 3276800  reads (B*L, 128)
#define F_DIFF 14745600u   //   25600  que_diff (B*L)
// total = 14,771,200 floats = 59,084,800 bytes

// ---------- K1: gather + projections + softmax + diff ----------
__global__ __launch_bounds__(256) void k_pre(
    const int* __restrict__ q, const int* __restrict__ r,
    const float* __restrict__ k_emb, const float* __restrict__ v_emb,
    const float* __restrict__ Mk, const float* __restrict__ eW,
    const float* __restrict__ aW, const float* __restrict__ fW,
    const float* __restrict__ e_b, const float* __restrict__ a_b,
    const float* __restrict__ df_W, const float* __restrict__ df_b,
    float* __restrict__ wq, float* __restrict__ eq, float* __restrict__ aq,
    float* __restrict__ fkq, float* __restrict__ diffq)
{
    __shared__ float sk[PP * SD];
    __shared__ float sv[PP * SD];
    __shared__ float sout[PP * 449];

    const int tid = threadIdx.x;
    const int pos0 = blockIdx.x * PP;

    // load k, v for 16 positions into LDS via float4
    for (int i = tid; i < PP * 32; i += 256) {
        int p = i >> 5, j = i & 31;           // j = float4 index within row
        int pos = pos0 + p;
        int qv = q[pos];
        int rv = r[pos];
        float4 kf = ((const float4*)(k_emb + qv * D_))[j];
        float4 ve = ((const float4*)(v_emb + rv * D_))[j];
        ((float4*)(sk + p * SD))[j] = kf;
        float4 vf; vf.x = kf.x + ve.x; vf.y = kf.y + ve.y;
        vf.z = kf.z + ve.z; vf.w = kf.w + ve.w;
        ((float4*)(sv + p * SD))[j] = vf;
    }
    __syncthreads();

    // 448 output columns: [0,64)=logits(k,Mk)  [64,192)=e(v,e_W)
    // [192,320)=a(v,a_W)  [320,448)=fk(k, f_W right half)
    const int p  = tid & 15;   // position
    const int cg = tid >> 4;   // column sub-index (0..15)
    for (int cb = 0; cb < 448; cb += 16) {
        int c = cb + cg;
        const float* wrow;
        const float* in;
        int grp;
        if (c < 64)       { grp = 0; wrow = Mk + c * D_;                 in = sk; }
        else if (c < 192) { grp = 1; wrow = eW + (c - 64) * D_;          in = sv; }
        else if (c < 320) { grp = 2; wrow = aW + (c - 192) * D_;         in = sv; }
        else              { grp = 3; wrow = fW + (c - 320) * 256 + 128;  in = sk; }
        const float4* w4 = (const float4*)wrow;
        const float4* i4 = (const float4*)(in + p * SD);
        float acc = 0.f;
        #pragma unroll
        for (int j = 0; j < 32; j++) {
            float4 a = w4[j];
            float4 b = i4[j];
            acc = fmaf(a.x, b.x, fmaf(a.y, b.y, fmaf(a.z, b.z, fmaf(a.w, b.w, acc))));
        }
        float outv;
        if (grp == 0)      outv = acc;                              // raw logit
        else if (grp == 1) outv = fast_sigmoid(acc + e_b[c - 64]);
        else if (grp == 2) outv = fast_tanh(acc + a_b[c - 192]);
        else               outv = acc;                              // fk raw
        sout[p * 449 + c] = outv;
    }

    // que_diff = tanh(k . df_W + df_b), 16 lanes per position
    {
        int p2 = tid >> 4, ln = tid & 15;
        const float* skp = sk + p2 * SD;
        float s = 0.f;
        #pragma unroll
        for (int j = 0; j < 8; j++) {
            int d = ln * 8 + j;
            s = fmaf(skp[d], df_W[d], s);
        }
        s += __shfl_xor(s, 1); s += __shfl_xor(s, 2);
        s += __shfl_xor(s, 4); s += __shfl_xor(s, 8);
        if (ln == 0) diffq[pos0 + p2] = fast_tanh(s + df_b[0]);
    }
    __syncthreads();

    // softmax over sout[p][0..64)
    {
        int p2 = tid >> 4, ln = tid & 15;
        float* row = sout + p2 * 449;
        float v0 = row[ln], v1 = row[ln + 16], v2 = row[ln + 32], v3 = row[ln + 48];
        float mx = fmaxf(fmaxf(v0, v1), fmaxf(v2, v3));
        mx = fmaxf(mx, __shfl_xor(mx, 1)); mx = fmaxf(mx, __shfl_xor(mx, 2));
        mx = fmaxf(mx, __shfl_xor(mx, 4)); mx = fmaxf(mx, __shfl_xor(mx, 8));
        float e0 = __expf(v0 - mx), e1 = __expf(v1 - mx);
        float e2 = __expf(v2 - mx), e3 = __expf(v3 - mx);
        float s = e0 + e1 + e2 + e3;
        s += __shfl_xor(s, 1); s += __shfl_xor(s, 2);
        s += __shfl_xor(s, 4); s += __shfl_xor(s, 8);
        float inv = 1.f / s;
        row[ln] = e0 * inv; row[ln + 16] = e1 * inv;
        row[ln + 32] = e2 * inv; row[ln + 48] = e3 * inv;
    }
    __syncthreads();

    // coalesced store-out
    for (int idx = tid; idx < PP * 448; idx += 256) {
        int p3 = idx / 448;
        int c = idx - p3 * 448;
        float v = sout[p3 * 449 + c];
        int pos3 = pos0 + p3;
        if (c < 64)       wq[pos3 * 64 + c] = v;
        else if (c < 192) eq[pos3 * 128 + (c - 64)] = v;
        else if (c < 320) aq[pos3 * 128 + (c - 192)] = v;
        else              fkq[pos3 * 128 + (c - 320)] = v;
    }
}

// ---------- K2: the scan; thread = (b, d, m-quarter) ----------
__global__ __launch_bounds__(256) void k_scan(
    const float* __restrict__ wq, const float* __restrict__ eq,
    const float* __restrict__ aq, const float* __restrict__ Mv0,
    float* __restrict__ reads)
{
    const int tid = threadIdx.x;
    const int b = blockIdx.x >> 1;
    const int dbase = (blockIdx.x & 1) * 64;
    const int s = tid & 3;        // m-quarter: m in [16s, 16s+16)
    const int dl = tid >> 2;      // 0..63
    const int d = dbase + dl;

    float Mv[16];
    #pragma unroll
    for (int j = 0; j < 16; j++) Mv[j] = Mv0[(s * 16 + j) * D_ + d];

    const float* wrow = wq + b * L_ * M_ + s * 16;
    const float* erow = eq + b * L_ * D_ + d;
    const float* arow = aq + b * L_ * D_ + d;
    float* rrow = reads + b * L_ * D_ + d;

    for (int t = 0; t < L_; t++) {
        const float4* w4 = (const float4*)(wrow + t * M_);
        float4 w0 = w4[0], w1 = w4[1], w2 = w4[2], w3 = w4[3];
        float ev = erow[t * D_];
        float av = arow[t * D_];
        float ne = -ev;
        float w[16] = { w0.x, w0.y, w0.z, w0.w, w1.x, w1.y, w1.z, w1.w,
                        w2.x, w2.y, w2.z, w2.w, w3.x, w3.y, w3.z, w3.w };
        float rd = 0.f;
        #pragma unroll
        for (int j = 0; j < 16; j++) rd = fmaf(w[j], Mv[j], rd);   // read uses pre-update Mv
        #pragma unroll
        for (int j = 0; j < 16; j++) {
            // Mv = Mv*(1 - w*e) + w*a  ==  Mv + w*(a - e*Mv)
            Mv[j] = fmaf(w[j], fmaf(ne, Mv[j], av), Mv[j]);
        }
        rd += __shfl_xor(rd, 1);
        rd += __shfl_xor(rd, 2);
        if (s == 0) rrow[t * D_] = rd;
    }
}

// ---------- K3: f = tanh(reads@fW_left + fk + f_b); out = sigmoid(3*ab - diff) ----------
__global__ __launch_bounds__(256) void k_final(
    const float* __restrict__ reads, const float* __restrict__ fkq,
    const float* __restrict__ diffq, const float* __restrict__ fW,
    const float* __restrict__ f_b, const float* __restrict__ ab_W,
    const float* __restrict__ ab_b, float* __restrict__ out)
{
    __shared__ float sr[PP * SD];
    __shared__ float sf[PP * 129];

    const int tid = threadIdx.x;
    const int pos0 = blockIdx.x * PP;

    for (int i = tid; i < PP * 32; i += 256) {
        int p = i >> 5, j = i & 31;
        ((float4*)(sr + p * SD))[j] = ((const float4*)(reads + (pos0 + p) * D_))[j];
    }
    __syncthreads();

    const int p  = tid & 15;
    const int cg = tid >> 4;
    for (int cb = 0; cb < 128; cb += 16) {
        int c = cb + cg;
        const float4* w4 = (const float4*)(fW + c * 256);   // left half of f_W row
        const float4* i4 = (const float4*)(sr + p * SD);
        float acc = 0.f;
        #pragma unroll
        for (int j = 0; j < 32; j++) {
            float4 a = w4[j];
            float4 b = i4[j];
            acc = fmaf(a.x, b.x, fmaf(a.y, b.y, fmaf(a.z, b.z, fmaf(a.w, b.w, acc))));
        }
        acc += fkq[(pos0 + p) * D_ + c] + f_b[c];
        sf[p * 129 + c] = fast_tanh(acc);
    }
    __syncthreads();

    {
        int p2 = tid >> 4, ln = tid & 15;
        const float* sfp = sf + p2 * 129;
        float s = 0.f;
        #pragma unroll
        for (int j = 0; j < 8; j++) {
            int dd = ln * 8 + j;
            s = fmaf(sfp[dd], ab_W[dd], s);
        }
        s += __shfl_xor(s, 1); s += __shfl_xor(s, 2);
        s += __shfl_xor(s, 4); s += __shfl_xor(s, 8);
        if (ln == 0) {
            float abv = fast_tanh(s + ab_b[0]);
            float x = 3.f * abv - diffq[pos0 + p2];
            out[pos0 + p2] = fast_sigmoid(x);
        }
    }
}

// ---------- launch ----------
extern "C" void kernel_launch(void* const* d_in, const int* in_sizes, int n_in,
                              void* d_out, int out_size, void* d_ws, size_t ws_size,
                              hipStream_t stream)
{
    const int*   q     = (const int*)d_in[0];
    const int*   r     = (const int*)d_in[1];
    const float* k_emb = (const float*)d_in[2];
    const float* v_emb = (const float*)d_in[3];
    const float* Mk    = (const float*)d_in[4];
    const float* Mv0   = (const float*)d_in[5];
    const float* f_W   = (const float*)d_in[6];
    const float* f_b   = (const float*)d_in[7];
    const float* e_W   = (const float*)d_in[8];
    const float* e_b   = (const float*)d_in[9];
    const float* a_W   = (const float*)d_in[10];
    const float* a_b   = (const float*)d_in[11];
    const float* ab_W  = (const float*)d_in[12];
    const float* ab_b  = (const float*)d_in[13];
    const float* df_W  = (const float*)d_in[14];
    const float* df_b  = (const float*)d_in[15];

    float* ws = (float*)d_ws;
    float* out = (float*)d_out;

    // K1: gather + projections + softmax + diff  (25600/16 = 1600 blocks)
    k_pre<<<1600, 256, 0, stream>>>(
        q, r, k_emb, v_emb, Mk, e_W, a_W, f_W,
        e_b, a_b, df_W, df_b,
        ws + F_WQ, ws + F_EQ, ws + F_AQ, ws + F_FKQ, ws + F_DIFF);

    // K2: scan (128 b * 2 halves = 256 blocks)
    k_scan<<<256, 256, 0, stream>>>(
        ws + F_WQ, ws + F_EQ, ws + F_AQ, Mv0, ws + F_RD);

    // K3: final projection + epilogue
    k_final<<<1600, 256, 0, stream>>>(
        ws + F_RD, ws + F_FKQ, ws + F_DIFF, f_W,
        f_b, ab_W, ab_b, out);
}

// Round 4
// 225.076 us; speedup vs baseline: 2.1937x; 2.1937x over previous
//
#include <hip/hip_runtime.h>

typedef unsigned short ushort_t;
typedef short bf16x8 __attribute__((ext_vector_type(8)));
typedef float f32x4 __attribute__((ext_vector_type(4)));

#define B_ 128
#define L_ 200
#define D_ 128
#define M_ 64

// ---------- helpers ----------
__device__ __forceinline__ float fast_sigmoid(float x) {
    return 1.f / (1.f + __expf(-x));
}

__device__ __forceinline__ float fast_tanh(float x) {
    float xc = fminf(fmaxf(x, -15.f), 15.f);
    float e = __expf(2.f * xc);
    return (e - 1.f) / (e + 1.f);
}

__device__ __forceinline__ ushort_t f2bf(float f) {
    union { float f; unsigned int u; } x;
    x.f = f;
    unsigned int u = x.u;
    unsigned int r = (u + 0x7FFFu + ((u >> 16) & 1u)) >> 16;  // RNE
    return (ushort_t)r;
}

__device__ __forceinline__ uint4 pack8(float4 a, float4 b) {
    uint4 u;
    u.x = (unsigned)f2bf(a.x) | ((unsigned)f2bf(a.y) << 16);
    u.y = (unsigned)f2bf(a.z) | ((unsigned)f2bf(a.w) << 16);
    u.z = (unsigned)f2bf(b.x) | ((unsigned)f2bf(b.y) << 16);
    u.w = (unsigned)f2bf(b.z) | ((unsigned)f2bf(b.w) << 16);
    return u;
}

// ---------- workspace layout ----------
// float region:
#define F_WQ   0u          // 1638400  w     (B*L, 64)
#define F_EQ   1638400u    // 3276800  e     (B*L, 128)
#define F_AQ   4915200u    // 3276800  a     (B*L, 128)
#define F_FKQ  8192000u    // 3276800  fk    (B*L, 128)
#define F_RD   11468800u   // 3276800  reads (B*L, 128)
#define F_DIFF 14745600u   //   25600  que_diff (B*L)
#define F_PACK 14771200u   // ushort region starts here (byte offset 59084800, 16B aligned)
// ushort offsets within pack region:
//   Wpack: 57344 ushort  (448 cols x 128 d, B-frag order)
//   Fpack: 16384 ushort  (128 cols x 128 d, B-frag order)
#define WPACK_N 57344
#define FPACK_N 16384

// ---------- K0: pack weights into bf16 MFMA-B fragment order ----------
// B-frag for tile (nt, ks): ushort index ((nt*4+ks)*64 + lane)*8 + j
// holds W[col = nt*16 + (lane&15)][d = ks*32 + (lane>>4)*8 + j]
__global__ __launch_bounds__(256) void k_pack(
    const float* __restrict__ Mk, const float* __restrict__ eW,
    const float* __restrict__ aW, const float* __restrict__ fW,
    ushort_t* __restrict__ Wpack, ushort_t* __restrict__ Fpack)
{
    int i = blockIdx.x * 256 + threadIdx.x;
    if (i < WPACK_N) {
        int g = i >> 9, lane = (i >> 3) & 63, j = i & 7;
        int nt = g >> 2, ks = g & 3;
        int col = nt * 16 + (lane & 15);
        int d = ks * 32 + ((lane >> 4) << 3) + j;
        float v;
        if (col < 64)       v = Mk[col * 128 + d];
        else if (col < 192) v = eW[(col - 64) * 128 + d];
        else if (col < 320) v = aW[(col - 192) * 128 + d];
        else                v = fW[(col - 320) * 256 + 128 + d];  // right half: k
        Wpack[i] = f2bf(v);
    } else if (i < WPACK_N + FPACK_N) {
        int e = i - WPACK_N;
        int g = e >> 9, lane = (e >> 3) & 63, j = e & 7;
        int nt = g >> 2, ks = g & 3;
        int col = nt * 16 + (lane & 15);
        int d = ks * 32 + ((lane >> 4) << 3) + j;
        Fpack[e] = f2bf(fW[col * 256 + d]);  // left half: reads
    }
}

// ---------- K1: MFMA gather+projections+softmax+diff ----------
// block = 64 positions; wave w handles m-tile of 16 positions.
// N layout: nt 0-3 logits(k)  4-11 e(v)  12-19 a(v)  20-27 fk(k)
__global__ __launch_bounds__(256) void k_pre_mfma(
    const int* __restrict__ q, const int* __restrict__ r,
    const float* __restrict__ k_emb, const float* __restrict__ v_emb,
    const ushort_t* __restrict__ Wpack,
    const float* __restrict__ e_b, const float* __restrict__ a_b,
    const float* __restrict__ df_W, const float* __restrict__ df_b,
    float* __restrict__ wq, float* __restrict__ eq, float* __restrict__ aq,
    float* __restrict__ fkq, float* __restrict__ diffq)
{
    __shared__ ushort_t skA[8192];   // A-frag order: ((mtile*4+ks)*64+lane)*8+j
    __shared__ ushort_t svA[8192];
    __shared__ float slog[64 * 68];  // raw logits, padded stride

    const int tid = threadIdx.x;
    const int pos0 = blockIdx.x * 64;
    const int wave = tid >> 6;
    const int lane = tid & 63;

    // --- stage A (k and v) into LDS in fragment order, f32 -> bf16 ---
    #pragma unroll
    for (int i = 0; i < 4; i++) {
        int E = tid + 256 * i;              // 0..1023 entries, 8 elems each
        int mtile = E >> 8, ks = (E >> 6) & 3, le = E & 63;
        int prow = pos0 + mtile * 16 + (le & 15);
        int dof = ks * 32 + ((le >> 4) << 3);
        int qv = q[prow], rv = r[prow];
        const float4* kp = (const float4*)(k_emb + qv * 128 + dof);
        float4 ka = kp[0], kb = kp[1];
        const float4* vp = (const float4*)(v_emb + rv * 128 + dof);
        float4 va = vp[0], vb = vp[1];
        *(uint4*)&skA[E * 8] = pack8(ka, kb);
        float4 s0, s1;
        s0.x = ka.x + va.x; s0.y = ka.y + va.y; s0.z = ka.z + va.z; s0.w = ka.w + va.w;
        s1.x = kb.x + vb.x; s1.y = kb.y + vb.y; s1.z = kb.z + vb.z; s1.w = kb.w + vb.w;
        *(uint4*)&svA[E * 8] = pack8(s0, s1);
    }
    __syncthreads();

    // --- load A fragments (reused across all 28 N-tiles) ---
    bf16x8 ak[4], av[4];
    #pragma unroll
    for (int ks = 0; ks < 4; ks++) {
        ak[ks] = *(bf16x8*)&skA[((wave * 4 + ks) * 64 + lane) * 8];
        av[ks] = *(bf16x8*)&svA[((wave * 4 + ks) * 64 + lane) * 8];
    }

    const int col = lane & 15;
    const int quad = lane >> 4;
    const int rbase = wave * 16 + quad * 4;

    // --- main MFMA loop over 28 N-tiles ---
    for (int nt = 0; nt < 28; nt++) {
        f32x4 acc = {0.f, 0.f, 0.f, 0.f};
        const bool useK = (nt < 4) || (nt >= 20);
        #pragma unroll
        for (int ks = 0; ks < 4; ks++) {
            bf16x8 bfr = *(const bf16x8*)(Wpack + ((nt * 4 + ks) * 64 + lane) * 8);
            acc = __builtin_amdgcn_mfma_f32_16x16x32_bf16(useK ? ak[ks] : av[ks], bfr, acc, 0, 0, 0);
        }
        int n0 = nt * 16;
        if (nt < 4) {
            #pragma unroll
            for (int reg = 0; reg < 4; reg++)
                slog[(rbase + reg) * 68 + n0 + col] = acc[reg];
        } else if (nt < 12) {
            int c = n0 - 64 + col;
            float bias = e_b[c];
            #pragma unroll
            for (int reg = 0; reg < 4; reg++)
                eq[(pos0 + rbase + reg) * 128 + c] = fast_sigmoid(acc[reg] + bias);
        } else if (nt < 20) {
            int c = n0 - 192 + col;
            float bias = a_b[c];
            #pragma unroll
            for (int reg = 0; reg < 4; reg++)
                aq[(pos0 + rbase + reg) * 128 + c] = fast_tanh(acc[reg] + bias);
        } else {
            int c = n0 - 320 + col;
            #pragma unroll
            for (int reg = 0; reg < 4; reg++)
                fkq[(pos0 + rbase + reg) * 128 + c] = acc[reg];
        }
    }

    // --- que_diff: 4 threads per row, direct from global (L2-hot) ---
    {
        int row = tid >> 2, ln = tid & 3;
        int pos = pos0 + row;
        int qv = q[pos];
        const float4* kp = (const float4*)(k_emb + qv * 128) + ln * 8;
        const float4* dfp = (const float4*)df_W + ln * 8;
        float s = 0.f;
        #pragma unroll
        for (int j = 0; j < 8; j++) {
            float4 a = kp[j], b = dfp[j];
            s = fmaf(a.x, b.x, fmaf(a.y, b.y, fmaf(a.z, b.z, fmaf(a.w, b.w, s))));
        }
        s += __shfl_xor(s, 1); s += __shfl_xor(s, 2);
        if (ln == 0) diffq[pos] = fast_tanh(s + df_b[0]);
    }

    __syncthreads();

    // --- softmax over slog rows: 4 threads/row, 16 cols each ---
    {
        int row = tid >> 2, ln = tid & 3;
        const float* lr = slog + row * 68 + ln * 16;
        float v[16];
        #pragma unroll
        for (int j = 0; j < 16; j++) v[j] = lr[j];
        float mx = v[0];
        #pragma unroll
        for (int j = 1; j < 16; j++) mx = fmaxf(mx, v[j]);
        mx = fmaxf(mx, __shfl_xor(mx, 1));
        mx = fmaxf(mx, __shfl_xor(mx, 2));
        float s = 0.f;
        #pragma unroll
        for (int j = 0; j < 16; j++) { v[j] = __expf(v[j] - mx); s += v[j]; }
        s += __shfl_xor(s, 1); s += __shfl_xor(s, 2);
        float inv = 1.f / s;
        float* wout = wq + (pos0 + row) * 64 + ln * 16;
        #pragma unroll
        for (int j = 0; j < 16; j++) wout[j] = v[j] * inv;
    }
}

// ---------- K2: scan, 16-way m-split for occupancy ----------
__global__ __launch_bounds__(1024) void k_scan(
    const float* __restrict__ wq, const float* __restrict__ eq,
    const float* __restrict__ aq, const float* __restrict__ Mv0,
    float* __restrict__ reads)
{
    const int tid = threadIdx.x;
    const int b = blockIdx.x >> 1;
    const int dbase = (blockIdx.x & 1) * 64;
    const int s = tid & 15;       // m in [4s, 4s+4)
    const int d = dbase + (tid >> 4);

    float Mv[4];
    #pragma unroll
    for (int j = 0; j < 4; j++) Mv[j] = Mv0[(s * 4 + j) * D_ + d];

    const float* wrow = wq + b * L_ * M_ + s * 4;
    const float* erow = eq + b * L_ * D_ + d;
    const float* arow = aq + b * L_ * D_ + d;
    float* rrow = reads + b * L_ * D_ + d;

    for (int t = 0; t < L_; t++) {
        float4 w = *(const float4*)(wrow + t * M_);
        float ev = erow[t * D_];
        float av = arow[t * D_];
        float ne = -ev;
        float rd;
        rd = w.x * Mv[0];
        rd = fmaf(w.y, Mv[1], rd);
        rd = fmaf(w.z, Mv[2], rd);
        rd = fmaf(w.w, Mv[3], rd);
        Mv[0] = fmaf(w.x, fmaf(ne, Mv[0], av), Mv[0]);
        Mv[1] = fmaf(w.y, fmaf(ne, Mv[1], av), Mv[1]);
        Mv[2] = fmaf(w.z, fmaf(ne, Mv[2], av), Mv[2]);
        Mv[3] = fmaf(w.w, fmaf(ne, Mv[3], av), Mv[3]);
        rd += __shfl_xor(rd, 1);
        rd += __shfl_xor(rd, 2);
        rd += __shfl_xor(rd, 4);
        rd += __shfl_xor(rd, 8);
        if (s == 0) rrow[t * D_] = rd;
    }
}

// ---------- K3: MFMA f-GEMM + fused ab/out epilogue ----------
__global__ __launch_bounds__(256) void k_final_mfma(
    const float* __restrict__ reads, const float* __restrict__ fkq,
    const float* __restrict__ diffq, const ushort_t* __restrict__ Fpack,
    const float* __restrict__ f_b, const float* __restrict__ ab_W,
    const float* __restrict__ ab_b, float* __restrict__ out)
{
    __shared__ ushort_t srA[8192];

    const int tid = threadIdx.x;
    const int pos0 = blockIdx.x * 64;
    const int wave = tid >> 6;
    const int lane = tid & 63;

    // stage reads -> bf16 A-frag order
    #pragma unroll
    for (int i = 0; i < 4; i++) {
        int E = tid + 256 * i;
        int mtile = E >> 8, ks = (E >> 6) & 3, le = E & 63;
        int prow = pos0 + mtile * 16 + (le & 15);
        int dof = ks * 32 + ((le >> 4) << 3);
        const float4* rp = (const float4*)(reads + prow * 128 + dof);
        *(uint4*)&srA[E * 8] = pack8(rp[0], rp[1]);
    }
    __syncthreads();

    bf16x8 ar[4];
    #pragma unroll
    for (int ks = 0; ks < 4; ks++)
        ar[ks] = *(bf16x8*)&srA[((wave * 4 + ks) * 64 + lane) * 8];

    const int col = lane & 15;
    const int quad = lane >> 4;
    const int rbase = wave * 16 + quad * 4;

    float abacc[4] = {0.f, 0.f, 0.f, 0.f};

    for (int nt = 0; nt < 8; nt++) {
        f32x4 acc = {0.f, 0.f, 0.f, 0.f};
        #pragma unroll
        for (int ks = 0; ks < 4; ks++) {
            bf16x8 bfr = *(const bf16x8*)(Fpack + ((nt * 4 + ks) * 64 + lane) * 8);
            acc = __builtin_amdgcn_mfma_f32_16x16x32_bf16(ar[ks], bfr, acc, 0, 0, 0);
        }
        int c = nt * 16 + col;
        float fb = f_b[c];
        float abw = ab_W[c];
        #pragma unroll
        for (int reg = 0; reg < 4; reg++) {
            float fv = fast_tanh(acc[reg] + fkq[(pos0 + rbase + reg) * 128 + c] + fb);
            abacc[reg] = fmaf(abw, fv, abacc[reg]);
        }
    }

    // reduce each row-partial across the 16 lanes of the quad
    #pragma unroll
    for (int reg = 0; reg < 4; reg++) {
        float v = abacc[reg];
        v += __shfl_xor(v, 1); v += __shfl_xor(v, 2);
        v += __shfl_xor(v, 4); v += __shfl_xor(v, 8);
        abacc[reg] = v;
    }
    if (col == 0) {
        #pragma unroll
        for (int reg = 0; reg < 4; reg++) {
            int pos = pos0 + rbase + reg;
            float ab = fast_tanh(abacc[reg] + ab_b[0]);
            out[pos] = fast_sigmoid(3.f * ab - diffq[pos]);
        }
    }
}

// ---------- launch ----------
extern "C" void kernel_launch(void* const* d_in, const int* in_sizes, int n_in,
                              void* d_out, int out_size, void* d_ws, size_t ws_size,
                              hipStream_t stream)
{
    const int*   q     = (const int*)d_in[0];
    const int*   r     = (const int*)d_in[1];
    const float* k_emb = (const float*)d_in[2];
    const float* v_emb = (const float*)d_in[3];
    const float* Mk    = (const float*)d_in[4];
    const float* Mv0   = (const float*)d_in[5];
    const float* f_W   = (const float*)d_in[6];
    const float* f_b   = (const float*)d_in[7];
    const float* e_W   = (const float*)d_in[8];
    const float* e_b   = (const float*)d_in[9];
    const float* a_W   = (const float*)d_in[10];
    const float* a_b   = (const float*)d_in[11];
    const float* ab_W  = (const float*)d_in[12];
    const float* ab_b  = (const float*)d_in[13];
    const float* df_W  = (const float*)d_in[14];
    const float* df_b  = (const float*)d_in[15];

    float* ws = (float*)d_ws;
    float* out = (float*)d_out;
    ushort_t* Wpack = (ushort_t*)(ws + F_PACK);
    ushort_t* Fpack = Wpack + WPACK_N;

    // K0: pack weights to bf16 fragment layout (73728 elems)
    k_pack<<<288, 256, 0, stream>>>(Mk, e_W, a_W, f_W, Wpack, Fpack);

    // K1: MFMA projections + softmax + diff (25600/64 = 400 blocks)
    k_pre_mfma<<<400, 256, 0, stream>>>(
        q, r, k_emb, v_emb, Wpack, e_b, a_b, df_W, df_b,
        ws + F_WQ, ws + F_EQ, ws + F_AQ, ws + F_FKQ, ws + F_DIFF);

    // K2: scan (128 b * 2 d-halves, 1024 threads)
    k_scan<<<256, 1024, 0, stream>>>(
        ws + F_WQ, ws + F_EQ, ws + F_AQ, Mv0, ws + F_RD);

    // K3: final MFMA + epilogue (400 blocks)
    k_final_mfma<<<400, 256, 0, stream>>>(
        ws + F_RD, ws + F_FKQ, ws + F_DIFF, Fpack,
        f_b, ab_W, ab_b, out);
}

// Round 5
// 200.653 us; speedup vs baseline: 2.4607x; 1.1217x over previous
//
#include <hip/hip_runtime.h>

typedef unsigned short ushort_t;
typedef short bf16x8 __attribute__((ext_vector_type(8)));
typedef float f32x4 __attribute__((ext_vector_type(4)));

#define B_ 128
#define L_ 200
#define D_ 128
#define M_ 64

// ---------- helpers ----------
__device__ __forceinline__ float fast_sigmoid(float x) {
    return 1.f / (1.f + __expf(-x));
}

__device__ __forceinline__ float fast_tanh(float x) {
    float xc = fminf(fmaxf(x, -15.f), 15.f);
    float e = __expf(2.f * xc);
    return (e - 1.f) / (e + 1.f);
}

__device__ __forceinline__ ushort_t f2bf(float f) {
    union { float f; unsigned int u; } x;
    x.f = f;
    unsigned int u = x.u;
    unsigned int r = (u + 0x7FFFu + ((u >> 16) & 1u)) >> 16;  // RNE
    return (ushort_t)r;
}

__device__ __forceinline__ uint4 pack8(float4 a, float4 b) {
    uint4 u;
    u.x = (unsigned)f2bf(a.x) | ((unsigned)f2bf(a.y) << 16);
    u.y = (unsigned)f2bf(a.z) | ((unsigned)f2bf(a.w) << 16);
    u.z = (unsigned)f2bf(b.x) | ((unsigned)f2bf(b.y) << 16);
    u.w = (unsigned)f2bf(b.z) | ((unsigned)f2bf(b.w) << 16);
    return u;
}

// ---------- workspace layout (float offsets) ----------
#define F_WQ   0u          // 1638400  w       (B*L, 64)
#define F_EAQ  1638400u    // 6553600  e,a interleaved (B*L, 128, 2)
#define F_FKQ  8192000u    // 3276800  fk      (B*L, 128)
#define F_RD   11468800u   // 3276800  reads   (B*L, 128)
#define F_DIFF 14745600u   //   25600  que_diff (B*L)
#define F_PACK 14771200u   // ushort region starts here (16B aligned)
#define WPACK_N 57344
#define FPACK_N 16384

// ---------- K0: pack weights into bf16 MFMA-B fragment order ----------
// B-frag for tile (nt, ks): ushort index ((nt*4+ks)*64 + lane)*8 + j
// holds W[col = nt*16 + (lane&15)][d = ks*32 + (lane>>4)*8 + j]
__global__ __launch_bounds__(256) void k_pack(
    const float* __restrict__ Mk, const float* __restrict__ eW,
    const float* __restrict__ aW, const float* __restrict__ fW,
    ushort_t* __restrict__ Wpack, ushort_t* __restrict__ Fpack)
{
    int i = blockIdx.x * 256 + threadIdx.x;
    if (i < WPACK_N) {
        int g = i >> 9, lane = (i >> 3) & 63, j = i & 7;
        int nt = g >> 2, ks = g & 3;
        int col = nt * 16 + (lane & 15);
        int d = ks * 32 + ((lane >> 4) << 3) + j;
        float v;
        if (col < 64)       v = Mk[col * 128 + d];
        else if (col < 192) v = eW[(col - 64) * 128 + d];
        else if (col < 320) v = aW[(col - 192) * 128 + d];
        else                v = fW[(col - 320) * 256 + 128 + d];  // right half: k
        Wpack[i] = f2bf(v);
    } else if (i < WPACK_N + FPACK_N) {
        int e = i - WPACK_N;
        int g = e >> 9, lane = (e >> 3) & 63, j = e & 7;
        int nt = g >> 2, ks = g & 3;
        int col = nt * 16 + (lane & 15);
        int d = ks * 32 + ((lane >> 4) << 3) + j;
        Fpack[e] = f2bf(fW[col * 256 + d]);  // left half: reads
    }
}

__device__ __forceinline__ void loadB4(const ushort_t* __restrict__ base,
                                       int nt, int lane, bf16x8* b) {
    const ushort_t* p = base + (nt * 256 + lane) * 8;
    b[0] = *(const bf16x8*)(p);
    b[1] = *(const bf16x8*)(p + 512);
    b[2] = *(const bf16x8*)(p + 1024);
    b[3] = *(const bf16x8*)(p + 1536);
}

// ---------- K1: MFMA gather+projections+softmax+diff ----------
// grid = 800: blockIdx>>1 = 64-position group; blockIdx&1 = N-group.
//   ng==0: logits (nt 0-3, input k) + fk (nt 20-27, input k) + diff + softmax
//   ng==1: e (nt 4-11) and a (nt 12-19), input v, paired float2 epilogue
__global__ __launch_bounds__(256) void k_pre_mfma(
    const int* __restrict__ q, const int* __restrict__ r,
    const float* __restrict__ k_emb, const float* __restrict__ v_emb,
    const ushort_t* __restrict__ Wpack,
    const float* __restrict__ e_b, const float* __restrict__ a_b,
    const float* __restrict__ df_W, const float* __restrict__ df_b,
    float* __restrict__ wq, float* __restrict__ eaq,
    float* __restrict__ fkq, float* __restrict__ diffq)
{
    __shared__ ushort_t sA[8192];    // A-frags (k for ng0, v for ng1)
    __shared__ float slog[64 * 68];  // raw logits (ng0 only)

    const int tid = threadIdx.x;
    const int pos0 = (blockIdx.x >> 1) * 64;
    const int ng = blockIdx.x & 1;
    const int wave = tid >> 6;
    const int lane = tid & 63;

    // --- stage A into LDS in fragment order, f32 -> bf16 ---
    #pragma unroll
    for (int i = 0; i < 4; i++) {
        int E = tid + 256 * i;              // 1024 entries, 8 elems each
        int mtile = E >> 8, ks = (E >> 6) & 3, le = E & 63;
        int prow = pos0 + mtile * 16 + (le & 15);
        int dof = ks * 32 + ((le >> 4) << 3);
        int qv = q[prow];
        const float4* kp = (const float4*)(k_emb + qv * 128 + dof);
        float4 ka = kp[0], kb = kp[1];
        if (ng == 0) {
            *(uint4*)&sA[E * 8] = pack8(ka, kb);
        } else {
            int rv = r[prow];
            const float4* vp = (const float4*)(v_emb + rv * 128 + dof);
            float4 va = vp[0], vb = vp[1];
            float4 s0, s1;
            s0.x = ka.x + va.x; s0.y = ka.y + va.y; s0.z = ka.z + va.z; s0.w = ka.w + va.w;
            s1.x = kb.x + vb.x; s1.y = kb.y + vb.y; s1.z = kb.z + vb.z; s1.w = kb.w + vb.w;
            *(uint4*)&sA[E * 8] = pack8(s0, s1);
        }
    }
    __syncthreads();

    bf16x8 A[4];
    #pragma unroll
    for (int ks = 0; ks < 4; ks++)
        A[ks] = *(bf16x8*)&sA[((wave * 4 + ks) * 64 + lane) * 8];

    const int col = lane & 15;
    const int quad = lane >> 4;
    const int rbase = wave * 16 + quad * 4;

    if (ng == 0) {
        // 12 nts: j 0-3 -> nt j (logits), j 4-11 -> nt j+16 (fk)
        bf16x8 Bb[2][4];
        loadB4(Wpack, 0, lane, Bb[0]);
        #pragma unroll
        for (int j = 0; j < 12; j++) {
            if (j < 11) {
                int jn = j + 1;
                loadB4(Wpack, (jn < 4) ? jn : jn + 16, lane, Bb[jn & 1]);
            }
            f32x4 acc = {0.f, 0.f, 0.f, 0.f};
            #pragma unroll
            for (int ks = 0; ks < 4; ks++)
                acc = __builtin_amdgcn_mfma_f32_16x16x32_bf16(A[ks], Bb[j & 1][ks], acc, 0, 0, 0);
            if (j < 4) {
                #pragma unroll
                for (int reg = 0; reg < 4; reg++)
                    slog[(rbase + reg) * 68 + j * 16 + col] = acc[reg];
            } else {
                int c = (j - 4) * 16 + col;
                #pragma unroll
                for (int reg = 0; reg < 4; reg++)
                    fkq[(pos0 + rbase + reg) * 128 + c] = acc[reg];
            }
        }

        // --- que_diff: 4 threads per row ---
        {
            int row = tid >> 2, ln = tid & 3;
            int pos = pos0 + row;
            int qv = q[pos];
            const float4* kp = (const float4*)(k_emb + qv * 128) + ln * 8;
            const float4* dfp = (const float4*)df_W + ln * 8;
            float s = 0.f;
            #pragma unroll
            for (int j = 0; j < 8; j++) {
                float4 a = kp[j], b = dfp[j];
                s = fmaf(a.x, b.x, fmaf(a.y, b.y, fmaf(a.z, b.z, fmaf(a.w, b.w, s))));
            }
            s += __shfl_xor(s, 1); s += __shfl_xor(s, 2);
            if (ln == 0) diffq[pos] = fast_tanh(s + df_b[0]);
        }

        __syncthreads();

        // --- softmax over slog rows: 4 threads/row, 16 cols each ---
        {
            int row = tid >> 2, ln = tid & 3;
            const float* lr = slog + row * 68 + ln * 16;
            float v[16];
            #pragma unroll
            for (int j = 0; j < 16; j++) v[j] = lr[j];
            float mx = v[0];
            #pragma unroll
            for (int j = 1; j < 16; j++) mx = fmaxf(mx, v[j]);
            mx = fmaxf(mx, __shfl_xor(mx, 1));
            mx = fmaxf(mx, __shfl_xor(mx, 2));
            float s = 0.f;
            #pragma unroll
            for (int j = 0; j < 16; j++) { v[j] = __expf(v[j] - mx); s += v[j]; }
            s += __shfl_xor(s, 1); s += __shfl_xor(s, 2);
            float inv = 1.f / s;
            float* wout = wq + (pos0 + row) * 64 + ln * 16;
            #pragma unroll
            for (int j = 0; j < 16; j++) wout[j] = v[j] * inv;
        }
    } else {
        // 8 paired nts: e = nt 4+i, a = nt 12+i; fused float2 store
        bf16x8 Be[2][4], Ba[2][4];
        loadB4(Wpack, 4, lane, Be[0]);
        loadB4(Wpack, 12, lane, Ba[0]);
        #pragma unroll
        for (int i = 0; i < 8; i++) {
            if (i < 7) {
                loadB4(Wpack, 5 + i, lane, Be[(i + 1) & 1]);
                loadB4(Wpack, 13 + i, lane, Ba[(i + 1) & 1]);
            }
            f32x4 ae = {0.f, 0.f, 0.f, 0.f};
            f32x4 aa = {0.f, 0.f, 0.f, 0.f};
            #pragma unroll
            for (int ks = 0; ks < 4; ks++) {
                ae = __builtin_amdgcn_mfma_f32_16x16x32_bf16(A[ks], Be[i & 1][ks], ae, 0, 0, 0);
                aa = __builtin_amdgcn_mfma_f32_16x16x32_bf16(A[ks], Ba[i & 1][ks], aa, 0, 0, 0);
            }
            int c = i * 16 + col;
            float ebv = e_b[c], abv = a_b[c];
            #pragma unroll
            for (int reg = 0; reg < 4; reg++) {
                float2 o;
                o.x = fast_sigmoid(ae[reg] + ebv);
                o.y = fast_tanh(aa[reg] + abv);
                *(float2*)(eaq + ((pos0 + rbase + reg) * 128 + c) * 2) = o;
            }
        }
    }
}

// ---------- K2: scan, 8-way m-split, register double-buffered ----------
__global__ __launch_bounds__(256) void k_scan(
    const float* __restrict__ wq, const float* __restrict__ eaq,
    const float* __restrict__ Mv0, float* __restrict__ reads)
{
    const int tid = threadIdx.x;
    const int b = blockIdx.x >> 2;
    const int dq = (blockIdx.x & 3) * 32;
    const int s = tid & 7;        // m in [8s, 8s+8)
    const int d = dq + (tid >> 3);

    float Mv[8];
    #pragma unroll
    for (int j = 0; j < 8; j++) Mv[j] = Mv0[(s * 8 + j) * D_ + d];

    const float* wrow = wq + b * L_ * M_ + s * 8;
    const float2* earow = (const float2*)eaq + b * L_ * D_ + d;
    float* rrow = reads + b * L_ * D_ + d;

    float4 wa0, wb0, wa1, wb1;
    float2 ea0, ea1;
    wa0 = *(const float4*)(wrow);
    wb0 = *(const float4*)(wrow + 4);
    ea0 = earow[0];

    for (int t = 0; t < L_; t += 2) {
        // prefetch t+1 (always valid: t <= 198)
        wa1 = *(const float4*)(wrow + (t + 1) * 64);
        wb1 = *(const float4*)(wrow + (t + 1) * 64 + 4);
        ea1 = earow[(t + 1) * 128];
        // compute t from buf0
        {
            float ev = ea0.x, av = ea0.y, ne = -ev;
            float r0 = wa0.x * Mv[0];
            float r1 = wa0.y * Mv[1];
            r0 = fmaf(wa0.z, Mv[2], r0); r1 = fmaf(wa0.w, Mv[3], r1);
            r0 = fmaf(wb0.x, Mv[4], r0); r1 = fmaf(wb0.y, Mv[5], r1);
            r0 = fmaf(wb0.z, Mv[6], r0); r1 = fmaf(wb0.w, Mv[7], r1);
            Mv[0] = fmaf(wa0.x, fmaf(ne, Mv[0], av), Mv[0]);
            Mv[1] = fmaf(wa0.y, fmaf(ne, Mv[1], av), Mv[1]);
            Mv[2] = fmaf(wa0.z, fmaf(ne, Mv[2], av), Mv[2]);
            Mv[3] = fmaf(wa0.w, fmaf(ne, Mv[3], av), Mv[3]);
            Mv[4] = fmaf(wb0.x, fmaf(ne, Mv[4], av), Mv[4]);
            Mv[5] = fmaf(wb0.y, fmaf(ne, Mv[5], av), Mv[5]);
            Mv[6] = fmaf(wb0.z, fmaf(ne, Mv[6], av), Mv[6]);
            Mv[7] = fmaf(wb0.w, fmaf(ne, Mv[7], av), Mv[7]);
            float rd = r0 + r1;
            rd += __shfl_xor(rd, 1);
            rd += __shfl_xor(rd, 2);
            rd += __shfl_xor(rd, 4);
            if (s == 0) rrow[t * D_] = rd;
        }
        // prefetch t+2
        if (t + 2 < L_) {
            wa0 = *(const float4*)(wrow + (t + 2) * 64);
            wb0 = *(const float4*)(wrow + (t + 2) * 64 + 4);
            ea0 = earow[(t + 2) * 128];
        }
        // compute t+1 from buf1
        {
            float ev = ea1.x, av = ea1.y, ne = -ev;
            float r0 = wa1.x * Mv[0];
            float r1 = wa1.y * Mv[1];
            r0 = fmaf(wa1.z, Mv[2], r0); r1 = fmaf(wa1.w, Mv[3], r1);
            r0 = fmaf(wb1.x, Mv[4], r0); r1 = fmaf(wb1.y, Mv[5], r1);
            r0 = fmaf(wb1.z, Mv[6], r0); r1 = fmaf(wb1.w, Mv[7], r1);
            Mv[0] = fmaf(wa1.x, fmaf(ne, Mv[0], av), Mv[0]);
            Mv[1] = fmaf(wa1.y, fmaf(ne, Mv[1], av), Mv[1]);
            Mv[2] = fmaf(wa1.z, fmaf(ne, Mv[2], av), Mv[2]);
            Mv[3] = fmaf(wa1.w, fmaf(ne, Mv[3], av), Mv[3]);
            Mv[4] = fmaf(wb1.x, fmaf(ne, Mv[4], av), Mv[4]);
            Mv[5] = fmaf(wb1.y, fmaf(ne, Mv[5], av), Mv[5]);
            Mv[6] = fmaf(wb1.z, fmaf(ne, Mv[6], av), Mv[6]);
            Mv[7] = fmaf(wb1.w, fmaf(ne, Mv[7], av), Mv[7]);
            float rd = r0 + r1;
            rd += __shfl_xor(rd, 1);
            rd += __shfl_xor(rd, 2);
            rd += __shfl_xor(rd, 4);
            if (s == 0) rrow[(t + 1) * D_] = rd;
        }
    }
}

// ---------- K3: MFMA f-GEMM + fused ab/out epilogue (8 waves) ----------
__global__ __launch_bounds__(512) void k_final_mfma(
    const float* __restrict__ reads, const float* __restrict__ fkq,
    const float* __restrict__ diffq, const ushort_t* __restrict__ Fpack,
    const float* __restrict__ f_b, const float* __restrict__ ab_W,
    const float* __restrict__ ab_b, float* __restrict__ out)
{
    __shared__ ushort_t srA[8192];
    __shared__ float sab[64 * 2];

    const int tid = threadIdx.x;
    const int pos0 = blockIdx.x * 64;
    const int wave = tid >> 6;
    const int lane = tid & 63;
    const int mt = wave & 3;        // m-tile
    const int half = wave >> 2;     // nt half: 0 -> nts 0-3, 1 -> nts 4-7

    // stage reads -> bf16 A-frag order (1024 entries, 2 per thread)
    #pragma unroll
    for (int i = 0; i < 2; i++) {
        int E = tid + 512 * i;
        int mtile = E >> 8, ks = (E >> 6) & 3, le = E & 63;
        int prow = pos0 + mtile * 16 + (le & 15);
        int dof = ks * 32 + ((le >> 4) << 3);
        const float4* rp = (const float4*)(reads + prow * 128 + dof);
        *(uint4*)&srA[E * 8] = pack8(rp[0], rp[1]);
    }
    __syncthreads();

    bf16x8 A[4];
    #pragma unroll
    for (int ks = 0; ks < 4; ks++)
        A[ks] = *(bf16x8*)&srA[((mt * 4 + ks) * 64 + lane) * 8];

    const int col = lane & 15;
    const int quad = lane >> 4;
    const int rbase = mt * 16 + quad * 4;

    float abacc[4] = {0.f, 0.f, 0.f, 0.f};

    bf16x8 Bb[2][4];
    loadB4(Fpack, half * 4, lane, Bb[0]);
    #pragma unroll
    for (int i = 0; i < 4; i++) {
        if (i < 3) loadB4(Fpack, half * 4 + i + 1, lane, Bb[(i + 1) & 1]);
        f32x4 acc = {0.f, 0.f, 0.f, 0.f};
        #pragma unroll
        for (int ks = 0; ks < 4; ks++)
            acc = __builtin_amdgcn_mfma_f32_16x16x32_bf16(A[ks], Bb[i & 1][ks], acc, 0, 0, 0);
        int c = (half * 4 + i) * 16 + col;
        float fb = f_b[c];
        float abw = ab_W[c];
        #pragma unroll
        for (int reg = 0; reg < 4; reg++) {
            float fv = fast_tanh(acc[reg] + fkq[(pos0 + rbase + reg) * 128 + c] + fb);
            abacc[reg] = fmaf(abw, fv, abacc[reg]);
        }
    }

    #pragma unroll
    for (int reg = 0; reg < 4; reg++) {
        float v = abacc[reg];
        v += __shfl_xor(v, 1); v += __shfl_xor(v, 2);
        v += __shfl_xor(v, 4); v += __shfl_xor(v, 8);
        abacc[reg] = v;
    }
    if (col == 0) {
        #pragma unroll
        for (int reg = 0; reg < 4; reg++)
            sab[(rbase + reg) * 2 + half] = abacc[reg];
    }
    __syncthreads();
    if (tid < 64) {
        float ab = fast_tanh(sab[tid * 2] + sab[tid * 2 + 1] + ab_b[0]);
        int pos = pos0 + tid;
        out[pos] = fast_sigmoid(3.f * ab - diffq[pos]);
    }
}

// ---------- launch ----------
extern "C" void kernel_launch(void* const* d_in, const int* in_sizes, int n_in,
                              void* d_out, int out_size, void* d_ws, size_t ws_size,
                              hipStream_t stream)
{
    const int*   q     = (const int*)d_in[0];
    const int*   r     = (const int*)d_in[1];
    const float* k_emb = (const float*)d_in[2];
    const float* v_emb = (const float*)d_in[3];
    const float* Mk    = (const float*)d_in[4];
    const float* Mv0   = (const float*)d_in[5];
    const float* f_W   = (const float*)d_in[6];
    const float* f_b   = (const float*)d_in[7];
    const float* e_W   = (const float*)d_in[8];
    const float* e_b   = (const float*)d_in[9];
    const float* a_W   = (const float*)d_in[10];
    const float* a_b   = (const float*)d_in[11];
    const float* ab_W  = (const float*)d_in[12];
    const float* ab_b  = (const float*)d_in[13];
    const float* df_W  = (const float*)d_in[14];
    const float* df_b  = (const float*)d_in[15];

    float* ws = (float*)d_ws;
    float* out = (float*)d_out;
    ushort_t* Wpack = (ushort_t*)(ws + F_PACK);
    ushort_t* Fpack = Wpack + WPACK_N;

    // K0: pack weights to bf16 fragment layout
    k_pack<<<288, 256, 0, stream>>>(Mk, e_W, a_W, f_W, Wpack, Fpack);

    // K1: MFMA projections + softmax + diff (400 pos-groups x 2 N-groups)
    k_pre_mfma<<<800, 256, 0, stream>>>(
        q, r, k_emb, v_emb, Wpack, e_b, a_b, df_W, df_b,
        ws + F_WQ, ws + F_EAQ, ws + F_FKQ, ws + F_DIFF);

    // K2: scan (128 b x 4 d-quarters, 256 threads: 32 d x 8 s)
    k_scan<<<512, 256, 0, stream>>>(
        ws + F_WQ, ws + F_EAQ, Mv0, ws + F_RD);

    // K3: final MFMA + epilogue (400 blocks x 8 waves)
    k_final_mfma<<<400, 512, 0, stream>>>(
        ws + F_RD, ws + F_FKQ, ws + F_DIFF, Fpack,
        f_b, ab_W, ab_b, out);
}

// Round 6
// 165.825 us; speedup vs baseline: 2.9775x; 1.2100x over previous
//
#include <hip/hip_runtime.h>

typedef unsigned short ushort_t;
typedef short bf16x8 __attribute__((ext_vector_type(8)));
typedef float f32x4 __attribute__((ext_vector_type(4)));

#define B_ 128
#define L_ 200
#define D_ 128
#define M_ 64

// ---------- helpers ----------
__device__ __forceinline__ float fast_sigmoid(float x) {
    return 1.f / (1.f + __expf(-x));
}

__device__ __forceinline__ float fast_tanh(float x) {
    float xc = fminf(fmaxf(x, -15.f), 15.f);
    float e = __expf(2.f * xc);
    return (e - 1.f) / (e + 1.f);
}

__device__ __forceinline__ ushort_t f2bf(float f) {
    union { float f; unsigned int u; } x;
    x.f = f;
    unsigned int u = x.u;
    unsigned int r = (u + 0x7FFFu + ((u >> 16) & 1u)) >> 16;  // RNE
    return (ushort_t)r;
}

__device__ __forceinline__ uint4 pack8(float4 a, float4 b) {
    uint4 u;
    u.x = (unsigned)f2bf(a.x) | ((unsigned)f2bf(a.y) << 16);
    u.y = (unsigned)f2bf(a.z) | ((unsigned)f2bf(a.w) << 16);
    u.z = (unsigned)f2bf(b.x) | ((unsigned)f2bf(b.y) << 16);
    u.w = (unsigned)f2bf(b.z) | ((unsigned)f2bf(b.w) << 16);
    return u;
}

// ---------- workspace layout (float offsets) ----------
#define F_WQ   0u          // 1638400  w       (B*L, 64)
#define F_EAQ  1638400u    // 6553600  e,a interleaved (B*L, 128, 2)
#define F_FKQ  8192000u    // 3276800  fk      (B*L, 128)
#define F_RD   11468800u   // 3276800  reads   (B*L, 128)
#define F_DIFF 14745600u   //   25600  que_diff (B*L)
#define F_PACK 14771200u   // ushort region starts here (16B aligned)
#define WPACK_N 57344
#define FPACK_N 16384

// ---------- K0: pack weights into bf16 MFMA-B fragment order ----------
__global__ __launch_bounds__(256) void k_pack(
    const float* __restrict__ Mk, const float* __restrict__ eW,
    const float* __restrict__ aW, const float* __restrict__ fW,
    ushort_t* __restrict__ Wpack, ushort_t* __restrict__ Fpack)
{
    int i = blockIdx.x * 256 + threadIdx.x;
    if (i < WPACK_N) {
        int g = i >> 9, lane = (i >> 3) & 63, j = i & 7;
        int nt = g >> 2, ks = g & 3;
        int col = nt * 16 + (lane & 15);
        int d = ks * 32 + ((lane >> 4) << 3) + j;
        float v;
        if (col < 64)       v = Mk[col * 128 + d];
        else if (col < 192) v = eW[(col - 64) * 128 + d];
        else if (col < 320) v = aW[(col - 192) * 128 + d];
        else                v = fW[(col - 320) * 256 + 128 + d];  // right half: k
        Wpack[i] = f2bf(v);
    } else if (i < WPACK_N + FPACK_N) {
        int e = i - WPACK_N;
        int g = e >> 9, lane = (e >> 3) & 63, j = e & 7;
        int nt = g >> 2, ks = g & 3;
        int col = nt * 16 + (lane & 15);
        int d = ks * 32 + ((lane >> 4) << 3) + j;
        Fpack[e] = f2bf(fW[col * 256 + d]);  // left half: reads
    }
}

__device__ __forceinline__ void loadB4(const ushort_t* __restrict__ base,
                                       int nt, int lane, bf16x8* b) {
    const ushort_t* p = base + (nt * 256 + lane) * 8;
    b[0] = *(const bf16x8*)(p);
    b[1] = *(const bf16x8*)(p + 512);
    b[2] = *(const bf16x8*)(p + 1024);
    b[3] = *(const bf16x8*)(p + 1536);
}

// ---------- K1: MFMA gather+projections+softmax+diff ----------
// grid = 800: blockIdx>>1 = 64-position group; blockIdx&1 = N-group.
//   ng==0: logits (nt 0-3, input k) + fk (nt 20-27, input k) + diff + softmax
//   ng==1: e (nt 4-11) and a (nt 12-19), input v, paired float2 epilogue
__global__ __launch_bounds__(256) void k_pre_mfma(
    const int* __restrict__ q, const int* __restrict__ r,
    const float* __restrict__ k_emb, const float* __restrict__ v_emb,
    const ushort_t* __restrict__ Wpack,
    const float* __restrict__ e_b, const float* __restrict__ a_b,
    const float* __restrict__ df_W, const float* __restrict__ df_b,
    float* __restrict__ wq, float* __restrict__ eaq,
    float* __restrict__ fkq, float* __restrict__ diffq)
{
    __shared__ ushort_t sA[8192];    // A-frags (k for ng0, v for ng1)
    __shared__ float slog[64 * 68];  // raw logits (ng0 only)

    const int tid = threadIdx.x;
    const int pos0 = (blockIdx.x >> 1) * 64;
    const int ng = blockIdx.x & 1;
    const int wave = tid >> 6;
    const int lane = tid & 63;

    // --- stage A into LDS in fragment order, f32 -> bf16 ---
    #pragma unroll
    for (int i = 0; i < 4; i++) {
        int E = tid + 256 * i;              // 1024 entries, 8 elems each
        int mtile = E >> 8, ks = (E >> 6) & 3, le = E & 63;
        int prow = pos0 + mtile * 16 + (le & 15);
        int dof = ks * 32 + ((le >> 4) << 3);
        int qv = q[prow];
        const float4* kp = (const float4*)(k_emb + qv * 128 + dof);
        float4 ka = kp[0], kb = kp[1];
        if (ng == 0) {
            *(uint4*)&sA[E * 8] = pack8(ka, kb);
        } else {
            int rv = r[prow];
            const float4* vp = (const float4*)(v_emb + rv * 128 + dof);
            float4 va = vp[0], vb = vp[1];
            float4 s0, s1;
            s0.x = ka.x + va.x; s0.y = ka.y + va.y; s0.z = ka.z + va.z; s0.w = ka.w + va.w;
            s1.x = kb.x + vb.x; s1.y = kb.y + vb.y; s1.z = kb.z + vb.z; s1.w = kb.w + vb.w;
            *(uint4*)&sA[E * 8] = pack8(s0, s1);
        }
    }
    __syncthreads();

    bf16x8 A[4];
    #pragma unroll
    for (int ks = 0; ks < 4; ks++)
        A[ks] = *(bf16x8*)&sA[((wave * 4 + ks) * 64 + lane) * 8];

    const int col = lane & 15;
    const int quad = lane >> 4;
    const int rbase = wave * 16 + quad * 4;

    if (ng == 0) {
        // 12 nts: j 0-3 -> nt j (logits), j 4-11 -> nt j+16 (fk)
        bf16x8 Bb[2][4];
        loadB4(Wpack, 0, lane, Bb[0]);
        #pragma unroll
        for (int j = 0; j < 12; j++) {
            if (j < 11) {
                int jn = j + 1;
                loadB4(Wpack, (jn < 4) ? jn : jn + 16, lane, Bb[jn & 1]);
            }
            f32x4 acc = {0.f, 0.f, 0.f, 0.f};
            #pragma unroll
            for (int ks = 0; ks < 4; ks++)
                acc = __builtin_amdgcn_mfma_f32_16x16x32_bf16(A[ks], Bb[j & 1][ks], acc, 0, 0, 0);
            if (j < 4) {
                #pragma unroll
                for (int reg = 0; reg < 4; reg++)
                    slog[(rbase + reg) * 68 + j * 16 + col] = acc[reg];
            } else {
                int c = (j - 4) * 16 + col;
                #pragma unroll
                for (int reg = 0; reg < 4; reg++)
                    fkq[(pos0 + rbase + reg) * 128 + c] = acc[reg];
            }
        }

        // --- que_diff: 4 threads per row ---
        {
            int row = tid >> 2, ln = tid & 3;
            int pos = pos0 + row;
            int qv = q[pos];
            const float4* kp = (const float4*)(k_emb + qv * 128) + ln * 8;
            const float4* dfp = (const float4*)df_W + ln * 8;
            float s = 0.f;
            #pragma unroll
            for (int j = 0; j < 8; j++) {
                float4 a = kp[j], b = dfp[j];
                s = fmaf(a.x, b.x, fmaf(a.y, b.y, fmaf(a.z, b.z, fmaf(a.w, b.w, s))));
            }
            s += __shfl_xor(s, 1); s += __shfl_xor(s, 2);
            if (ln == 0) diffq[pos] = fast_tanh(s + df_b[0]);
        }

        __syncthreads();

        // --- softmax over slog rows: 4 threads/row, 16 cols each ---
        {
            int row = tid >> 2, ln = tid & 3;
            const float* lr = slog + row * 68 + ln * 16;
            float v[16];
            #pragma unroll
            for (int j = 0; j < 16; j++) v[j] = lr[j];
            float mx = v[0];
            #pragma unroll
            for (int j = 1; j < 16; j++) mx = fmaxf(mx, v[j]);
            mx = fmaxf(mx, __shfl_xor(mx, 1));
            mx = fmaxf(mx, __shfl_xor(mx, 2));
            float s = 0.f;
            #pragma unroll
            for (int j = 0; j < 16; j++) { v[j] = __expf(v[j] - mx); s += v[j]; }
            s += __shfl_xor(s, 1); s += __shfl_xor(s, 2);
            float inv = 1.f / s;
            float* wout = wq + (pos0 + row) * 64 + ln * 16;
            #pragma unroll
            for (int j = 0; j < 16; j++) wout[j] = v[j] * inv;
        }
    } else {
        // 8 paired nts: e = nt 4+i, a = nt 12+i; fused float2 store
        bf16x8 Be[2][4], Ba[2][4];
        loadB4(Wpack, 4, lane, Be[0]);
        loadB4(Wpack, 12, lane, Ba[0]);
        #pragma unroll
        for (int i = 0; i < 8; i++) {
            if (i < 7) {
                loadB4(Wpack, 5 + i, lane, Be[(i + 1) & 1]);
                loadB4(Wpack, 13 + i, lane, Ba[(i + 1) & 1]);
            }
            f32x4 ae = {0.f, 0.f, 0.f, 0.f};
            f32x4 aa = {0.f, 0.f, 0.f, 0.f};
            #pragma unroll
            for (int ks = 0; ks < 4; ks++) {
                ae = __builtin_amdgcn_mfma_f32_16x16x32_bf16(A[ks], Be[i & 1][ks], ae, 0, 0, 0);
                aa = __builtin_amdgcn_mfma_f32_16x16x32_bf16(A[ks], Ba[i & 1][ks], aa, 0, 0, 0);
            }
            int c = i * 16 + col;
            float ebv = e_b[c], abv = a_b[c];
            #pragma unroll
            for (int reg = 0; reg < 4; reg++) {
                float2 o;
                o.x = fast_sigmoid(ae[reg] + ebv);
                o.y = fast_tanh(aa[reg] + abv);
                *(float2*)(eaq + ((pos0 + rbase + reg) * 128 + c) * 2) = o;
            }
        }
    }
}

// ---------- K2: scan — LDS double-buffered chunks of 8 timesteps ----------
// block: b = blockIdx>>2, dq = (blockIdx&3)*32; 256 thr = 32 d x 8 s
__global__ __launch_bounds__(256) void k_scan(
    const float* __restrict__ wq, const float* __restrict__ eaq,
    const float* __restrict__ Mv0, float* __restrict__ reads)
{
    __shared__ float w_lds[2][512];
    __shared__ float ea_lds[2][512];

    const int tid = threadIdx.x;
    const int b = blockIdx.x >> 2;
    const int dq = (blockIdx.x & 3) * 32;
    const int s = tid & 7;        // m in [8s, 8s+8)
    const int dl = tid >> 3;      // 0..31
    const int d = dq + dl;

    float Mv[8];
    #pragma unroll
    for (int j = 0; j < 8; j++) Mv[j] = Mv0[(s * 8 + j) * D_ + d];

    const float* wbase = wq + b * (L_ * M_);
    const float* eabase = eaq + b * (L_ * 256) + dq * 2;
    float* rrow = reads + b * (L_ * D_) + d;

    // loader role: tid<128 loads w (512 floats/chunk contiguous), else ea
    const bool is_w = (tid < 128);
    const int li = is_w ? tid : (tid - 128);     // 0..127, one float4 each
    const int ett = li >> 4;                      // ea: timestep in chunk
    const int ejj = (li & 15) * 4;                // ea: float offset in row-slice

    // preload chunk 0
    {
        float4 st;
        if (is_w) st = *(const float4*)(wbase + li * 4);
        else      st = *(const float4*)(eabase + ett * 256 + ejj);
        float* dst = is_w ? &w_lds[0][li * 4] : &ea_lds[0][li * 4];
        *(float4*)dst = st;
    }
    __syncthreads();

    int buf = 0;
    for (int c = 0; c < 25; c++) {
        const int t0 = c * 8;
        // issue next chunk's global loads into registers (latency hidden by compute)
        float4 nst;
        if (c < 24) {
            if (is_w) nst = *(const float4*)(wbase + (t0 + 8) * 64 + li * 4);
            else      nst = *(const float4*)(eabase + (t0 + 8 + ett) * 256 + ejj);
        }
        // compute 8 timesteps from LDS front buffer
        #pragma unroll
        for (int tt = 0; tt < 8; tt++) {
            float4 wa = *(const float4*)&w_lds[buf][tt * 64 + s * 8];
            float4 wb = *(const float4*)&w_lds[buf][tt * 64 + s * 8 + 4];
            float2 ea = *(const float2*)&ea_lds[buf][tt * 64 + dl * 2];
            float ev = ea.x, av = ea.y, ne = -ev;
            float r0 = wa.x * Mv[0];
            float r1 = wa.y * Mv[1];
            r0 = fmaf(wa.z, Mv[2], r0); r1 = fmaf(wa.w, Mv[3], r1);
            r0 = fmaf(wb.x, Mv[4], r0); r1 = fmaf(wb.y, Mv[5], r1);
            r0 = fmaf(wb.z, Mv[6], r0); r1 = fmaf(wb.w, Mv[7], r1);
            Mv[0] = fmaf(wa.x, fmaf(ne, Mv[0], av), Mv[0]);
            Mv[1] = fmaf(wa.y, fmaf(ne, Mv[1], av), Mv[1]);
            Mv[2] = fmaf(wa.z, fmaf(ne, Mv[2], av), Mv[2]);
            Mv[3] = fmaf(wa.w, fmaf(ne, Mv[3], av), Mv[3]);
            Mv[4] = fmaf(wb.x, fmaf(ne, Mv[4], av), Mv[4]);
            Mv[5] = fmaf(wb.y, fmaf(ne, Mv[5], av), Mv[5]);
            Mv[6] = fmaf(wb.z, fmaf(ne, Mv[6], av), Mv[6]);
            Mv[7] = fmaf(wb.w, fmaf(ne, Mv[7], av), Mv[7]);
            float rd = r0 + r1;
            rd += __shfl_xor(rd, 1);
            rd += __shfl_xor(rd, 2);
            rd += __shfl_xor(rd, 4);
            if (s == 0) rrow[(t0 + tt) * D_] = rd;
        }
        // commit next chunk to back buffer
        if (c < 24) {
            float* dst = is_w ? &w_lds[buf ^ 1][li * 4] : &ea_lds[buf ^ 1][li * 4];
            *(float4*)dst = nst;
        }
        __syncthreads();
        buf ^= 1;
    }
}

// ---------- K3: MFMA f-GEMM + fused ab/out epilogue (8 waves) ----------
__global__ __launch_bounds__(512) void k_final_mfma(
    const float* __restrict__ reads, const float* __restrict__ fkq,
    const float* __restrict__ diffq, const ushort_t* __restrict__ Fpack,
    const float* __restrict__ f_b, const float* __restrict__ ab_W,
    const float* __restrict__ ab_b, float* __restrict__ out)
{
    __shared__ ushort_t srA[8192];
    __shared__ float sab[64 * 2];

    const int tid = threadIdx.x;
    const int pos0 = blockIdx.x * 64;
    const int wave = tid >> 6;
    const int lane = tid & 63;
    const int mt = wave & 3;        // m-tile
    const int half = wave >> 2;     // nt half: 0 -> nts 0-3, 1 -> nts 4-7

    // stage reads -> bf16 A-frag order (1024 entries, 2 per thread)
    #pragma unroll
    for (int i = 0; i < 2; i++) {
        int E = tid + 512 * i;
        int mtile = E >> 8, ks = (E >> 6) & 3, le = E & 63;
        int prow = pos0 + mtile * 16 + (le & 15);
        int dof = ks * 32 + ((le >> 4) << 3);
        const float4* rp = (const float4*)(reads + prow * 128 + dof);
        *(uint4*)&srA[E * 8] = pack8(rp[0], rp[1]);
    }
    __syncthreads();

    bf16x8 A[4];
    #pragma unroll
    for (int ks = 0; ks < 4; ks++)
        A[ks] = *(bf16x8*)&srA[((mt * 4 + ks) * 64 + lane) * 8];

    const int col = lane & 15;
    const int quad = lane >> 4;
    const int rbase = mt * 16 + quad * 4;

    float abacc[4] = {0.f, 0.f, 0.f, 0.f};

    bf16x8 Bb[2][4];
    loadB4(Fpack, half * 4, lane, Bb[0]);
    #pragma unroll
    for (int i = 0; i < 4; i++) {
        if (i < 3) loadB4(Fpack, half * 4 + i + 1, lane, Bb[(i + 1) & 1]);
        f32x4 acc = {0.f, 0.f, 0.f, 0.f};
        #pragma unroll
        for (int ks = 0; ks < 4; ks++)
            acc = __builtin_amdgcn_mfma_f32_16x16x32_bf16(A[ks], Bb[i & 1][ks], acc, 0, 0, 0);
        int c = (half * 4 + i) * 16 + col;
        float fb = f_b[c];
        float abw = ab_W[c];
        #pragma unroll
        for (int reg = 0; reg < 4; reg++) {
            float fv = fast_tanh(acc[reg] + fkq[(pos0 + rbase + reg) * 128 + c] + fb);
            abacc[reg] = fmaf(abw, fv, abacc[reg]);
        }
    }

    #pragma unroll
    for (int reg = 0; reg < 4; reg++) {
        float v = abacc[reg];
        v += __shfl_xor(v, 1); v += __shfl_xor(v, 2);
        v += __shfl_xor(v, 4); v += __shfl_xor(v, 8);
        abacc[reg] = v;
    }
    if (col == 0) {
        #pragma unroll
        for (int reg = 0; reg < 4; reg++)
            sab[(rbase + reg) * 2 + half] = abacc[reg];
    }
    __syncthreads();
    if (tid < 64) {
        float ab = fast_tanh(sab[tid * 2] + sab[tid * 2 + 1] + ab_b[0]);
        int pos = pos0 + tid;
        out[pos] = fast_sigmoid(3.f * ab - diffq[pos]);
    }
}

// ---------- launch ----------
extern "C" void kernel_launch(void* const* d_in, const int* in_sizes, int n_in,
                              void* d_out, int out_size, void* d_ws, size_t ws_size,
                              hipStream_t stream)
{
    const int*   q     = (const int*)d_in[0];
    const int*   r     = (const int*)d_in[1];
    const float* k_emb = (const float*)d_in[2];
    const float* v_emb = (const float*)d_in[3];
    const float* Mk    = (const float*)d_in[4];
    const float* Mv0   = (const float*)d_in[5];
    const float* f_W   = (const float*)d_in[6];
    const float* f_b   = (const float*)d_in[7];
    const float* e_W   = (const float*)d_in[8];
    const float* e_b   = (const float*)d_in[9];
    const float* a_W   = (const float*)d_in[10];
    const float* a_b   = (const float*)d_in[11];
    const float* ab_W  = (const float*)d_in[12];
    const float* ab_b  = (const float*)d_in[13];
    const float* df_W  = (const float*)d_in[14];
    const float* df_b  = (const float*)d_in[15];

    float* ws = (float*)d_ws;
    float* out = (float*)d_out;
    ushort_t* Wpack = (ushort_t*)(ws + F_PACK);
    ushort_t* Fpack = Wpack + WPACK_N;

    // K0: pack weights to bf16 fragment layout
    k_pack<<<288, 256, 0, stream>>>(Mk, e_W, a_W, f_W, Wpack, Fpack);

    // K1: MFMA projections + softmax + diff (400 pos-groups x 2 N-groups)
    k_pre_mfma<<<800, 256, 0, stream>>>(
        q, r, k_emb, v_emb, Wpack, e_b, a_b, df_W, df_b,
        ws + F_WQ, ws + F_EAQ, ws + F_FKQ, ws + F_DIFF);

    // K2: scan (128 b x 4 d-quarters, LDS-chunked)
    k_scan<<<512, 256, 0, stream>>>(
        ws + F_WQ, ws + F_EAQ, Mv0, ws + F_RD);

    // K3: final MFMA + epilogue (400 blocks x 8 waves)
    k_final_mfma<<<400, 512, 0, stream>>>(
        ws + F_RD, ws + F_FKQ, ws + F_DIFF, Fpack,
        f_b, ab_W, ab_b, out);
}

// Round 7
// 160.210 us; speedup vs baseline: 3.0819x; 1.0350x over previous
//
#include <hip/hip_runtime.h>

typedef unsigned short ushort_t;
typedef short bf16x8 __attribute__((ext_vector_type(8)));
typedef float f32x4 __attribute__((ext_vector_type(4)));

#define B_ 128
#define L_ 200
#define D_ 128
#define M_ 64

// ---------- helpers ----------
__device__ __forceinline__ float fast_sigmoid(float x) {
    return 1.f / (1.f + __expf(-x));
}

__device__ __forceinline__ float fast_tanh(float x) {
    float xc = fminf(fmaxf(x, -15.f), 15.f);
    float e = __expf(2.f * xc);
    return (e - 1.f) / (e + 1.f);
}

__device__ __forceinline__ ushort_t f2bf(float f) {
    union { float f; unsigned int u; } x;
    x.f = f;
    unsigned int u = x.u;
    unsigned int r = (u + 0x7FFFu + ((u >> 16) & 1u)) >> 16;  // RNE
    return (ushort_t)r;
}

__device__ __forceinline__ uint4 pack8(float4 a, float4 b) {
    uint4 u;
    u.x = (unsigned)f2bf(a.x) | ((unsigned)f2bf(a.y) << 16);
    u.y = (unsigned)f2bf(a.z) | ((unsigned)f2bf(a.w) << 16);
    u.z = (unsigned)f2bf(b.x) | ((unsigned)f2bf(b.y) << 16);
    u.w = (unsigned)f2bf(b.z) | ((unsigned)f2bf(b.w) << 16);
    return u;
}

// ---------- workspace layout (float offsets) ----------
#define F_WQ   0u          // 1638400  w       (B*L, 64)
#define F_EAQ  1638400u    // 6553600  e,a interleaved (B*L, 128, 2)
#define F_FKQ  8192000u    // 3276800  fk      (B*L, 128)
#define F_RD   11468800u   // 3276800  reads   (B*L, 128)
#define F_DIFF 14745600u   //   25600  que_diff (B*L)
#define F_PACK 14771200u   // ushort region starts here (16B aligned)
#define WPACK_N 57344
#define FPACK_N 16384

// ---------- K0: pack weights into bf16 MFMA-B fragment order ----------
__global__ __launch_bounds__(256) void k_pack(
    const float* __restrict__ Mk, const float* __restrict__ eW,
    const float* __restrict__ aW, const float* __restrict__ fW,
    ushort_t* __restrict__ Wpack, ushort_t* __restrict__ Fpack)
{
    int i = blockIdx.x * 256 + threadIdx.x;
    if (i < WPACK_N) {
        int g = i >> 9, lane = (i >> 3) & 63, j = i & 7;
        int nt = g >> 2, ks = g & 3;
        int col = nt * 16 + (lane & 15);
        int d = ks * 32 + ((lane >> 4) << 3) + j;
        float v;
        if (col < 64)       v = Mk[col * 128 + d];
        else if (col < 192) v = eW[(col - 64) * 128 + d];
        else if (col < 320) v = aW[(col - 192) * 128 + d];
        else                v = fW[(col - 320) * 256 + 128 + d];  // right half: k
        Wpack[i] = f2bf(v);
    } else if (i < WPACK_N + FPACK_N) {
        int e = i - WPACK_N;
        int g = e >> 9, lane = (e >> 3) & 63, j = e & 7;
        int nt = g >> 2, ks = g & 3;
        int col = nt * 16 + (lane & 15);
        int d = ks * 32 + ((lane >> 4) << 3) + j;
        Fpack[e] = f2bf(fW[col * 256 + d]);  // left half: reads
    }
}

__device__ __forceinline__ void loadB4(const ushort_t* __restrict__ base,
                                       int nt, int lane, bf16x8* b) {
    const ushort_t* p = base + (nt * 256 + lane) * 8;
    b[0] = *(const bf16x8*)(p);
    b[1] = *(const bf16x8*)(p + 512);
    b[2] = *(const bf16x8*)(p + 1024);
    b[3] = *(const bf16x8*)(p + 1536);
}

// ---------- K1: MFMA gather+projections+softmax+diff ----------
// grid = 800: blockIdx>>1 = 64-position group; blockIdx&1 = N-group.
//   ng==0: logits (nt 0-3, input k) + fk (nt 20-27, input k) + diff + softmax
//   ng==1: e (nt 4-11) and a (nt 12-19), input v, paired float2 epilogue
__global__ __launch_bounds__(256) void k_pre_mfma(
    const int* __restrict__ q, const int* __restrict__ r,
    const float* __restrict__ k_emb, const float* __restrict__ v_emb,
    const ushort_t* __restrict__ Wpack,
    const float* __restrict__ e_b, const float* __restrict__ a_b,
    const float* __restrict__ df_W, const float* __restrict__ df_b,
    float* __restrict__ wq, float* __restrict__ eaq,
    float* __restrict__ fkq, float* __restrict__ diffq)
{
    __shared__ ushort_t sA[8192];    // A-frags (k for ng0, v for ng1)
    __shared__ float slog[64 * 68];  // raw logits (ng0 only)

    const int tid = threadIdx.x;
    const int pos0 = (blockIdx.x >> 1) * 64;
    const int ng = blockIdx.x & 1;
    const int wave = tid >> 6;
    const int lane = tid & 63;

    // --- stage A into LDS in fragment order, f32 -> bf16 ---
    #pragma unroll
    for (int i = 0; i < 4; i++) {
        int E = tid + 256 * i;              // 1024 entries, 8 elems each
        int mtile = E >> 8, ks = (E >> 6) & 3, le = E & 63;
        int prow = pos0 + mtile * 16 + (le & 15);
        int dof = ks * 32 + ((le >> 4) << 3);
        int qv = q[prow];
        const float4* kp = (const float4*)(k_emb + qv * 128 + dof);
        float4 ka = kp[0], kb = kp[1];
        if (ng == 0) {
            *(uint4*)&sA[E * 8] = pack8(ka, kb);
        } else {
            int rv = r[prow];
            const float4* vp = (const float4*)(v_emb + rv * 128 + dof);
            float4 va = vp[0], vb = vp[1];
            float4 s0, s1;
            s0.x = ka.x + va.x; s0.y = ka.y + va.y; s0.z = ka.z + va.z; s0.w = ka.w + va.w;
            s1.x = kb.x + vb.x; s1.y = kb.y + vb.y; s1.z = kb.z + vb.z; s1.w = kb.w + vb.w;
            *(uint4*)&sA[E * 8] = pack8(s0, s1);
        }
    }
    __syncthreads();

    bf16x8 A[4];
    #pragma unroll
    for (int ks = 0; ks < 4; ks++)
        A[ks] = *(bf16x8*)&sA[((wave * 4 + ks) * 64 + lane) * 8];

    const int col = lane & 15;
    const int quad = lane >> 4;
    const int rbase = wave * 16 + quad * 4;

    if (ng == 0) {
        // 12 nts: j 0-3 -> nt j (logits), j 4-11 -> nt j+16 (fk)
        bf16x8 Bb[2][4];
        loadB4(Wpack, 0, lane, Bb[0]);
        #pragma unroll
        for (int j = 0; j < 12; j++) {
            if (j < 11) {
                int jn = j + 1;
                loadB4(Wpack, (jn < 4) ? jn : jn + 16, lane, Bb[jn & 1]);
            }
            f32x4 acc = {0.f, 0.f, 0.f, 0.f};
            #pragma unroll
            for (int ks = 0; ks < 4; ks++)
                acc = __builtin_amdgcn_mfma_f32_16x16x32_bf16(A[ks], Bb[j & 1][ks], acc, 0, 0, 0);
            if (j < 4) {
                #pragma unroll
                for (int reg = 0; reg < 4; reg++)
                    slog[(rbase + reg) * 68 + j * 16 + col] = acc[reg];
            } else {
                int c = (j - 4) * 16 + col;
                #pragma unroll
                for (int reg = 0; reg < 4; reg++)
                    fkq[(pos0 + rbase + reg) * 128 + c] = acc[reg];
            }
        }

        // --- que_diff: 4 threads per row ---
        {
            int row = tid >> 2, ln = tid & 3;
            int pos = pos0 + row;
            int qv = q[pos];
            const float4* kp = (const float4*)(k_emb + qv * 128) + ln * 8;
            const float4* dfp = (const float4*)df_W + ln * 8;
            float s = 0.f;
            #pragma unroll
            for (int j = 0; j < 8; j++) {
                float4 a = kp[j], b = dfp[j];
                s = fmaf(a.x, b.x, fmaf(a.y, b.y, fmaf(a.z, b.z, fmaf(a.w, b.w, s))));
            }
            s += __shfl_xor(s, 1); s += __shfl_xor(s, 2);
            if (ln == 0) diffq[pos] = fast_tanh(s + df_b[0]);
        }

        __syncthreads();

        // --- softmax over slog rows: 4 threads/row, 16 cols each ---
        {
            int row = tid >> 2, ln = tid & 3;
            const float* lr = slog + row * 68 + ln * 16;
            float v[16];
            #pragma unroll
            for (int j = 0; j < 16; j++) v[j] = lr[j];
            float mx = v[0];
            #pragma unroll
            for (int j = 1; j < 16; j++) mx = fmaxf(mx, v[j]);
            mx = fmaxf(mx, __shfl_xor(mx, 1));
            mx = fmaxf(mx, __shfl_xor(mx, 2));
            float s = 0.f;
            #pragma unroll
            for (int j = 0; j < 16; j++) { v[j] = __expf(v[j] - mx); s += v[j]; }
            s += __shfl_xor(s, 1); s += __shfl_xor(s, 2);
            float inv = 1.f / s;
            float* wout = wq + (pos0 + row) * 64 + ln * 16;
            #pragma unroll
            for (int j = 0; j < 16; j++) wout[j] = v[j] * inv;
        }
    } else {
        // 8 paired nts: e = nt 4+i, a = nt 12+i; fused float2 store
        bf16x8 Be[2][4], Ba[2][4];
        loadB4(Wpack, 4, lane, Be[0]);
        loadB4(Wpack, 12, lane, Ba[0]);
        #pragma unroll
        for (int i = 0; i < 8; i++) {
            if (i < 7) {
                loadB4(Wpack, 5 + i, lane, Be[(i + 1) & 1]);
                loadB4(Wpack, 13 + i, lane, Ba[(i + 1) & 1]);
            }
            f32x4 ae = {0.f, 0.f, 0.f, 0.f};
            f32x4 aa = {0.f, 0.f, 0.f, 0.f};
            #pragma unroll
            for (int ks = 0; ks < 4; ks++) {
                ae = __builtin_amdgcn_mfma_f32_16x16x32_bf16(A[ks], Be[i & 1][ks], ae, 0, 0, 0);
                aa = __builtin_amdgcn_mfma_f32_16x16x32_bf16(A[ks], Ba[i & 1][ks], aa, 0, 0, 0);
            }
            int c = i * 16 + col;
            float ebv = e_b[c], abv = a_b[c];
            #pragma unroll
            for (int reg = 0; reg < 4; reg++) {
                float2 o;
                o.x = fast_sigmoid(ae[reg] + ebv);
                o.y = fast_tanh(aa[reg] + abv);
                *(float2*)(eaq + ((pos0 + rbase + reg) * 128 + c) * 2) = o;
            }
        }
    }
}

// ---------- K2: scan — wave-uniform w, no-LDS hot loop, chunked read-reduce ----------
// grid = 256: b = blockIdx>>1, d-half = blockIdx&1. 256 thr = 4 waves.
// wave sc covers m in [sc*16, sc*16+16) for all 64 d of the half.
__global__ __launch_bounds__(256) void k_scan(
    const float* __restrict__ wq, const float* __restrict__ eaq,
    const float* __restrict__ Mv0, float* __restrict__ reads)
{
    __shared__ float pbuf[2][4][8][64];   // [buf][sc][tt][d] partial reads

    const int tid = threadIdx.x;
    const int b = blockIdx.x >> 1;
    const int dh = blockIdx.x & 1;
    const int sc = __builtin_amdgcn_readfirstlane(tid >> 6);  // wave id, uniform
    const int lane = tid & 63;
    const int d = dh * 64 + lane;

    float Mv[16];
    #pragma unroll
    for (int j = 0; j < 16; j++) Mv[j] = Mv0[(sc * 16 + j) * D_ + d];

    const float4* wbase = (const float4*)(wq + b * (L_ * M_) + sc * 16);
    const float2* eabase = (const float2*)(eaq + b * (L_ * 256)) + d;
    float* rbase = reads + b * (L_ * D_) + dh * 64;

    const int rtt = tid >> 6;        // reduce: entry0 tt = rtt, entry1 tt = rtt+4
    const int rdd = tid & 63;

    for (int c = 0; c < 25; c++) {
        const int t0 = c * 8;
        const int bb = c & 1;
        // compute 8 timesteps, no LDS reads, loads direct from global (L1/L2-hot)
        #pragma unroll
        for (int tt = 0; tt < 8; tt++) {
            const float4* wp = wbase + (t0 + tt) * 16;
            float4 w0 = wp[0], w1 = wp[1], w2 = wp[2], w3 = wp[3];
            float2 ea = eabase[(t0 + tt) * 128];
            float ev = ea.x, av = ea.y, ne = -ev;
            float r0, r1;
            r0 = w0.x * Mv[0];
            r1 = w0.y * Mv[1];
            r0 = fmaf(w0.z, Mv[2], r0);  r1 = fmaf(w0.w, Mv[3], r1);
            r0 = fmaf(w1.x, Mv[4], r0);  r1 = fmaf(w1.y, Mv[5], r1);
            r0 = fmaf(w1.z, Mv[6], r0);  r1 = fmaf(w1.w, Mv[7], r1);
            r0 = fmaf(w2.x, Mv[8], r0);  r1 = fmaf(w2.y, Mv[9], r1);
            r0 = fmaf(w2.z, Mv[10], r0); r1 = fmaf(w2.w, Mv[11], r1);
            r0 = fmaf(w3.x, Mv[12], r0); r1 = fmaf(w3.y, Mv[13], r1);
            r0 = fmaf(w3.z, Mv[14], r0); r1 = fmaf(w3.w, Mv[15], r1);
            Mv[0]  = fmaf(w0.x, fmaf(ne, Mv[0],  av), Mv[0]);
            Mv[1]  = fmaf(w0.y, fmaf(ne, Mv[1],  av), Mv[1]);
            Mv[2]  = fmaf(w0.z, fmaf(ne, Mv[2],  av), Mv[2]);
            Mv[3]  = fmaf(w0.w, fmaf(ne, Mv[3],  av), Mv[3]);
            Mv[4]  = fmaf(w1.x, fmaf(ne, Mv[4],  av), Mv[4]);
            Mv[5]  = fmaf(w1.y, fmaf(ne, Mv[5],  av), Mv[5]);
            Mv[6]  = fmaf(w1.z, fmaf(ne, Mv[6],  av), Mv[6]);
            Mv[7]  = fmaf(w1.w, fmaf(ne, Mv[7],  av), Mv[7]);
            Mv[8]  = fmaf(w2.x, fmaf(ne, Mv[8],  av), Mv[8]);
            Mv[9]  = fmaf(w2.y, fmaf(ne, Mv[9],  av), Mv[9]);
            Mv[10] = fmaf(w2.z, fmaf(ne, Mv[10], av), Mv[10]);
            Mv[11] = fmaf(w2.w, fmaf(ne, Mv[11], av), Mv[11]);
            Mv[12] = fmaf(w3.x, fmaf(ne, Mv[12], av), Mv[12]);
            Mv[13] = fmaf(w3.y, fmaf(ne, Mv[13], av), Mv[13]);
            Mv[14] = fmaf(w3.z, fmaf(ne, Mv[14], av), Mv[14]);
            Mv[15] = fmaf(w3.w, fmaf(ne, Mv[15], av), Mv[15]);
            pbuf[bb][sc][tt][lane] = r0 + r1;
        }
        __syncthreads();
        // cross-wave reduce of this chunk: 512 outputs, 2 per thread
        {
            float s0 = pbuf[bb][0][rtt][rdd] + pbuf[bb][1][rtt][rdd]
                     + pbuf[bb][2][rtt][rdd] + pbuf[bb][3][rtt][rdd];
            float s1 = pbuf[bb][0][rtt + 4][rdd] + pbuf[bb][1][rtt + 4][rdd]
                     + pbuf[bb][2][rtt + 4][rdd] + pbuf[bb][3][rtt + 4][rdd];
            rbase[(t0 + rtt) * D_ + rdd] = s0;
            rbase[(t0 + rtt + 4) * D_ + rdd] = s1;
        }
    }
}

// ---------- K3: MFMA f-GEMM + fused ab/out epilogue (8 waves) ----------
__global__ __launch_bounds__(512) void k_final_mfma(
    const float* __restrict__ reads, const float* __restrict__ fkq,
    const float* __restrict__ diffq, const ushort_t* __restrict__ Fpack,
    const float* __restrict__ f_b, const float* __restrict__ ab_W,
    const float* __restrict__ ab_b, float* __restrict__ out)
{
    __shared__ ushort_t srA[8192];
    __shared__ float sab[64 * 2];

    const int tid = threadIdx.x;
    const int pos0 = blockIdx.x * 64;
    const int wave = tid >> 6;
    const int lane = tid & 63;
    const int mt = wave & 3;        // m-tile
    const int half = wave >> 2;     // nt half: 0 -> nts 0-3, 1 -> nts 4-7

    // stage reads -> bf16 A-frag order (1024 entries, 2 per thread)
    #pragma unroll
    for (int i = 0; i < 2; i++) {
        int E = tid + 512 * i;
        int mtile = E >> 8, ks = (E >> 6) & 3, le = E & 63;
        int prow = pos0 + mtile * 16 + (le & 15);
        int dof = ks * 32 + ((le >> 4) << 3);
        const float4* rp = (const float4*)(reads + prow * 128 + dof);
        *(uint4*)&srA[E * 8] = pack8(rp[0], rp[1]);
    }
    __syncthreads();

    bf16x8 A[4];
    #pragma unroll
    for (int ks = 0; ks < 4; ks++)
        A[ks] = *(bf16x8*)&srA[((mt * 4 + ks) * 64 + lane) * 8];

    const int col = lane & 15;
    const int quad = lane >> 4;
    const int rbase = mt * 16 + quad * 4;

    float abacc[4] = {0.f, 0.f, 0.f, 0.f};

    bf16x8 Bb[2][4];
    loadB4(Fpack, half * 4, lane, Bb[0]);
    #pragma unroll
    for (int i = 0; i < 4; i++) {
        if (i < 3) loadB4(Fpack, half * 4 + i + 1, lane, Bb[(i + 1) & 1]);
        f32x4 acc = {0.f, 0.f, 0.f, 0.f};
        #pragma unroll
        for (int ks = 0; ks < 4; ks++)
            acc = __builtin_amdgcn_mfma_f32_16x16x32_bf16(A[ks], Bb[i & 1][ks], acc, 0, 0, 0);
        int c = (half * 4 + i) * 16 + col;
        float fb = f_b[c];
        float abw = ab_W[c];
        #pragma unroll
        for (int reg = 0; reg < 4; reg++) {
            float fv = fast_tanh(acc[reg] + fkq[(pos0 + rbase + reg) * 128 + c] + fb);
            abacc[reg] = fmaf(abw, fv, abacc[reg]);
        }
    }

    #pragma unroll
    for (int reg = 0; reg < 4; reg++) {
        float v = abacc[reg];
        v += __shfl_xor(v, 1); v += __shfl_xor(v, 2);
        v += __shfl_xor(v, 4); v += __shfl_xor(v, 8);
        abacc[reg] = v;
    }
    if (col == 0) {
        #pragma unroll
        for (int reg = 0; reg < 4; reg++)
            sab[(rbase + reg) * 2 + half] = abacc[reg];
    }
    __syncthreads();
    if (tid < 64) {
        float ab = fast_tanh(sab[tid * 2] + sab[tid * 2 + 1] + ab_b[0]);
        int pos = pos0 + tid;
        out[pos] = fast_sigmoid(3.f * ab - diffq[pos]);
    }
}

// ---------- launch ----------
extern "C" void kernel_launch(void* const* d_in, const int* in_sizes, int n_in,
                              void* d_out, int out_size, void* d_ws, size_t ws_size,
                              hipStream_t stream)
{
    const int*   q     = (const int*)d_in[0];
    const int*   r     = (const int*)d_in[1];
    const float* k_emb = (const float*)d_in[2];
    const float* v_emb = (const float*)d_in[3];
    const float* Mk    = (const float*)d_in[4];
    const float* Mv0   = (const float*)d_in[5];
    const float* f_W   = (const float*)d_in[6];
    const float* f_b   = (const float*)d_in[7];
    const float* e_W   = (const float*)d_in[8];
    const float* e_b   = (const float*)d_in[9];
    const float* a_W   = (const float*)d_in[10];
    const float* a_b   = (const float*)d_in[11];
    const float* ab_W  = (const float*)d_in[12];
    const float* ab_b  = (const float*)d_in[13];
    const float* df_W  = (const float*)d_in[14];
    const float* df_b  = (const float*)d_in[15];

    float* ws = (float*)d_ws;
    float* out = (float*)d_out;
    ushort_t* Wpack = (ushort_t*)(ws + F_PACK);
    ushort_t* Fpack = Wpack + WPACK_N;

    // K0: pack weights to bf16 fragment layout
    k_pack<<<288, 256, 0, stream>>>(Mk, e_W, a_W, f_W, Wpack, Fpack);

    // K1: MFMA projections + softmax + diff (400 pos-groups x 2 N-groups)
    k_pre_mfma<<<800, 256, 0, stream>>>(
        q, r, k_emb, v_emb, Wpack, e_b, a_b, df_W, df_b,
        ws + F_WQ, ws + F_EAQ, ws + F_FKQ, ws + F_DIFF);

    // K2: scan (128 b x 2 d-halves, 4 waves each, 1 block/CU)
    k_scan<<<256, 256, 0, stream>>>(
        ws + F_WQ, ws + F_EAQ, Mv0, ws + F_RD);

    // K3: final MFMA + epilogue (400 blocks x 8 waves)
    k_final_mfma<<<400, 512, 0, stream>>>(
        ws + F_RD, ws + F_FKQ, ws + F_DIFF, Fpack,
        f_b, ab_W, ab_b, out);
}

// Round 8
// 151.214 us; speedup vs baseline: 3.2652x; 1.0595x over previous
//
#include <hip/hip_runtime.h>

typedef unsigned short ushort_t;
typedef short bf16x8 __attribute__((ext_vector_type(8)));
typedef float f32x4 __attribute__((ext_vector_type(4)));

#define B_ 128
#define L_ 200
#define D_ 128
#define M_ 64

// ---------- helpers ----------
__device__ __forceinline__ float fast_sigmoid(float x) {
    return 1.f / (1.f + __expf(-x));
}

__device__ __forceinline__ float fast_tanh(float x) {
    float xc = fminf(fmaxf(x, -15.f), 15.f);
    float e = __expf(2.f * xc);
    return (e - 1.f) / (e + 1.f);
}

__device__ __forceinline__ ushort_t f2bf(float f) {
    union { float f; unsigned int u; } x;
    x.f = f;
    unsigned int u = x.u;
    unsigned int r = (u + 0x7FFFu + ((u >> 16) & 1u)) >> 16;  // RNE
    return (ushort_t)r;
}

__device__ __forceinline__ uint4 pack8(float4 a, float4 b) {
    uint4 u;
    u.x = (unsigned)f2bf(a.x) | ((unsigned)f2bf(a.y) << 16);
    u.y = (unsigned)f2bf(a.z) | ((unsigned)f2bf(a.w) << 16);
    u.z = (unsigned)f2bf(b.x) | ((unsigned)f2bf(b.y) << 16);
    u.w = (unsigned)f2bf(b.z) | ((unsigned)f2bf(b.w) << 16);
    return u;
}

// ---------- workspace layout (float offsets) ----------
#define F_WQ   0u          // 1638400  w       (B*L, 64)
#define F_EAQ  1638400u    // 6553600  e,a interleaved (B*L, 128, 2)
#define F_FKQ  8192000u    // 3276800  fk      (B*L, 128)
#define F_RD   11468800u   // 3276800  reads   (B*L, 128)
#define F_DIFF 14745600u   //   25600  que_diff (B*L)
#define F_PACK 14771200u   // ushort region starts here (16B aligned)
#define WPACK_N 57344
#define FPACK_N 16384

// ---------- K0: pack weights into bf16 MFMA-B fragment order ----------
__global__ __launch_bounds__(256) void k_pack(
    const float* __restrict__ Mk, const float* __restrict__ eW,
    const float* __restrict__ aW, const float* __restrict__ fW,
    ushort_t* __restrict__ Wpack, ushort_t* __restrict__ Fpack)
{
    int i = blockIdx.x * 256 + threadIdx.x;
    if (i < WPACK_N) {
        int g = i >> 9, lane = (i >> 3) & 63, j = i & 7;
        int nt = g >> 2, ks = g & 3;
        int col = nt * 16 + (lane & 15);
        int d = ks * 32 + ((lane >> 4) << 3) + j;
        float v;
        if (col < 64)       v = Mk[col * 128 + d];
        else if (col < 192) v = eW[(col - 64) * 128 + d];
        else if (col < 320) v = aW[(col - 192) * 128 + d];
        else                v = fW[(col - 320) * 256 + 128 + d];  // right half: k
        Wpack[i] = f2bf(v);
    } else if (i < WPACK_N + FPACK_N) {
        int e = i - WPACK_N;
        int g = e >> 9, lane = (e >> 3) & 63, j = e & 7;
        int nt = g >> 2, ks = g & 3;
        int col = nt * 16 + (lane & 15);
        int d = ks * 32 + ((lane >> 4) << 3) + j;
        Fpack[e] = f2bf(fW[col * 256 + d]);  // left half: reads
    }
}

__device__ __forceinline__ void loadB4(const ushort_t* __restrict__ base,
                                       int nt, int lane, bf16x8* b) {
    const ushort_t* p = base + (nt * 256 + lane) * 8;
    b[0] = *(const bf16x8*)(p);
    b[1] = *(const bf16x8*)(p + 512);
    b[2] = *(const bf16x8*)(p + 1024);
    b[3] = *(const bf16x8*)(p + 1536);
}

// ---------- K1: unified MFMA gather+projections+softmax+diff ----------
// 400 blocks x 512 thr. One gather per 64-pos group (k and v both staged).
// waves 0-3 (nh=0): logits nt0-3 + fk nt20-27 (A=k), then softmax
// waves 4-7 (nh=1): e nt4-11 paired with a nt12-19 (A=v), then diff
__global__ __launch_bounds__(512) void k_pre_mfma(
    const int* __restrict__ q, const int* __restrict__ r,
    const float* __restrict__ k_emb, const float* __restrict__ v_emb,
    const ushort_t* __restrict__ Wpack,
    const float* __restrict__ e_b, const float* __restrict__ a_b,
    const float* __restrict__ df_W, const float* __restrict__ df_b,
    float* __restrict__ wq, float* __restrict__ eaq,
    float* __restrict__ fkq, float* __restrict__ diffq)
{
    __shared__ ushort_t skA[8192];
    __shared__ ushort_t svA[8192];
    __shared__ float slog[64 * 68];

    const int tid = threadIdx.x;
    const int pos0 = blockIdx.x * 64;
    const int wave = tid >> 6;
    const int lane = tid & 63;
    const int mt = wave & 3;
    const int nh = wave >> 2;

    // --- single gather: stage k and v A-frags (bf16) ---
    #pragma unroll
    for (int i = 0; i < 2; i++) {
        int E = tid + 512 * i;              // 1024 entries, 8 elems each
        int mtile = E >> 8, ks = (E >> 6) & 3, le = E & 63;
        int prow = pos0 + mtile * 16 + (le & 15);
        int dof = ks * 32 + ((le >> 4) << 3);
        int qv = q[prow], rv = r[prow];
        const float4* kp = (const float4*)(k_emb + qv * 128 + dof);
        float4 ka = kp[0], kb = kp[1];
        const float4* vp = (const float4*)(v_emb + rv * 128 + dof);
        float4 va = vp[0], vb = vp[1];
        *(uint4*)&skA[E * 8] = pack8(ka, kb);
        float4 s0, s1;
        s0.x = ka.x + va.x; s0.y = ka.y + va.y; s0.z = ka.z + va.z; s0.w = ka.w + va.w;
        s1.x = kb.x + vb.x; s1.y = kb.y + vb.y; s1.z = kb.z + vb.z; s1.w = kb.w + vb.w;
        *(uint4*)&svA[E * 8] = pack8(s0, s1);
    }
    __syncthreads();

    bf16x8 A[4];
    {
        const ushort_t* src = nh ? svA : skA;
        #pragma unroll
        for (int ks = 0; ks < 4; ks++)
            A[ks] = *(const bf16x8*)&src[((mt * 4 + ks) * 64 + lane) * 8];
    }

    const int col = lane & 15;
    const int quad = lane >> 4;
    const int rbase = mt * 16 + quad * 4;

    if (nh == 0) {
        // 12 nts: j 0-3 -> nt j (logits->slog), j 4-11 -> nt j+16 (fk)
        bf16x8 Bb[2][4];
        loadB4(Wpack, 0, lane, Bb[0]);
        #pragma unroll
        for (int j = 0; j < 12; j++) {
            if (j < 11) {
                int jn = j + 1;
                loadB4(Wpack, (jn < 4) ? jn : jn + 16, lane, Bb[jn & 1]);
            }
            f32x4 acc = {0.f, 0.f, 0.f, 0.f};
            #pragma unroll
            for (int ks = 0; ks < 4; ks++)
                acc = __builtin_amdgcn_mfma_f32_16x16x32_bf16(A[ks], Bb[j & 1][ks], acc, 0, 0, 0);
            if (j < 4) {
                #pragma unroll
                for (int reg = 0; reg < 4; reg++)
                    slog[(rbase + reg) * 68 + j * 16 + col] = acc[reg];
            } else {
                int c = (j - 4) * 16 + col;
                #pragma unroll
                for (int reg = 0; reg < 4; reg++)
                    fkq[(pos0 + rbase + reg) * 128 + c] = acc[reg];
            }
        }
        // softmax over own wave's slog rows (wave-local: rows mt*16..mt*16+15)
        {
            int row = tid >> 2, ln = tid & 3;   // tid<256: rows 0-63
            const float* lr = slog + row * 68 + ln * 16;
            float v[16];
            #pragma unroll
            for (int j = 0; j < 16; j++) v[j] = lr[j];
            float mx = v[0];
            #pragma unroll
            for (int j = 1; j < 16; j++) mx = fmaxf(mx, v[j]);
            mx = fmaxf(mx, __shfl_xor(mx, 1));
            mx = fmaxf(mx, __shfl_xor(mx, 2));
            float s = 0.f;
            #pragma unroll
            for (int j = 0; j < 16; j++) { v[j] = __expf(v[j] - mx); s += v[j]; }
            s += __shfl_xor(s, 1); s += __shfl_xor(s, 2);
            float inv = 1.f / s;
            float* wout = wq + (pos0 + row) * 64 + ln * 16;
            #pragma unroll
            for (int j = 0; j < 16; j++) wout[j] = v[j] * inv;
        }
    } else {
        // 8 paired nts: e = nt 4+i, a = nt 12+i; fused float2 store
        bf16x8 Be[2][4], Ba[2][4];
        loadB4(Wpack, 4, lane, Be[0]);
        loadB4(Wpack, 12, lane, Ba[0]);
        #pragma unroll
        for (int i = 0; i < 8; i++) {
            if (i < 7) {
                loadB4(Wpack, 5 + i, lane, Be[(i + 1) & 1]);
                loadB4(Wpack, 13 + i, lane, Ba[(i + 1) & 1]);
            }
            f32x4 ae = {0.f, 0.f, 0.f, 0.f};
            f32x4 aa = {0.f, 0.f, 0.f, 0.f};
            #pragma unroll
            for (int ks = 0; ks < 4; ks++) {
                ae = __builtin_amdgcn_mfma_f32_16x16x32_bf16(A[ks], Be[i & 1][ks], ae, 0, 0, 0);
                aa = __builtin_amdgcn_mfma_f32_16x16x32_bf16(A[ks], Ba[i & 1][ks], aa, 0, 0, 0);
            }
            int c = i * 16 + col;
            float ebv = e_b[c], abv = a_b[c];
            #pragma unroll
            for (int reg = 0; reg < 4; reg++) {
                float2 o;
                o.x = fast_sigmoid(ae[reg] + ebv);
                o.y = fast_tanh(aa[reg] + abv);
                *(float2*)(eaq + ((pos0 + rbase + reg) * 128 + c) * 2) = o;
            }
        }
        // que_diff: threads 256-511, 4 per row
        {
            int t2 = tid - 256;
            int row = t2 >> 2, ln = t2 & 3;
            int pos = pos0 + row;
            int qv = q[pos];
            const float4* kp = (const float4*)(k_emb + qv * 128) + ln * 8;
            const float4* dfp = (const float4*)df_W + ln * 8;
            float s = 0.f;
            #pragma unroll
            for (int j = 0; j < 8; j++) {
                float4 a = kp[j], b = dfp[j];
                s = fmaf(a.x, b.x, fmaf(a.y, b.y, fmaf(a.z, b.z, fmaf(a.w, b.w, s))));
            }
            s += __shfl_xor(s, 1); s += __shfl_xor(s, 2);
            if (ln == 0) diffq[pos] = fast_tanh(s + df_b[0]);
        }
    }
}

// ---------- K2: scan — 8 waves (8 m x 64 d), chunk-ahead register prefetch ----------
// grid 256: b = blk>>1, dh = blk&1. Chunk = 8 timesteps, A/B reg double-buffer.
#define SC_PREFETCH(wX, eX, cN)                                            \
    _Pragma("unroll")                                                      \
    for (int tt = 0; tt < 8; tt++) {                                       \
        wX[2 * tt]     = wb4[((cN) * 8 + tt) * 16 + sc * 2];               \
        wX[2 * tt + 1] = wb4[((cN) * 8 + tt) * 16 + sc * 2 + 1];           \
        eX[tt]         = eab[((cN) * 8 + tt) * 128];                       \
    }

#define SC_COMPUTE(wX, eX, bb)                                             \
    _Pragma("unroll")                                                      \
    for (int tt = 0; tt < 8; tt++) {                                       \
        float4 u = wX[2 * tt], v = wX[2 * tt + 1];                         \
        float2 ea = eX[tt];                                                \
        float ev = ea.x, av = ea.y, ne = -ev;                              \
        float r0 = u.x * Mv[0];                                            \
        float r1 = u.y * Mv[1];                                            \
        r0 = fmaf(u.z, Mv[2], r0); r1 = fmaf(u.w, Mv[3], r1);              \
        r0 = fmaf(v.x, Mv[4], r0); r1 = fmaf(v.y, Mv[5], r1);              \
        r0 = fmaf(v.z, Mv[6], r0); r1 = fmaf(v.w, Mv[7], r1);              \
        Mv[0] = fmaf(u.x, fmaf(ne, Mv[0], av), Mv[0]);                     \
        Mv[1] = fmaf(u.y, fmaf(ne, Mv[1], av), Mv[1]);                     \
        Mv[2] = fmaf(u.z, fmaf(ne, Mv[2], av), Mv[2]);                     \
        Mv[3] = fmaf(u.w, fmaf(ne, Mv[3], av), Mv[3]);                     \
        Mv[4] = fmaf(v.x, fmaf(ne, Mv[4], av), Mv[4]);                     \
        Mv[5] = fmaf(v.y, fmaf(ne, Mv[5], av), Mv[5]);                     \
        Mv[6] = fmaf(v.z, fmaf(ne, Mv[6], av), Mv[6]);                     \
        Mv[7] = fmaf(v.w, fmaf(ne, Mv[7], av), Mv[7]);                     \
        pbuf[bb][sc][tt][lane] = r0 + r1;                                  \
    }

#define SC_REDUCE(bb, c0) {                                                \
        float s = pbuf[bb][0][wv][lane] + pbuf[bb][1][wv][lane]            \
                + pbuf[bb][2][wv][lane] + pbuf[bb][3][wv][lane]            \
                + pbuf[bb][4][wv][lane] + pbuf[bb][5][wv][lane]            \
                + pbuf[bb][6][wv][lane] + pbuf[bb][7][wv][lane];           \
        rbase[((c0) * 8 + wv) * 128 + lane] = s;                           \
    }

__global__ __launch_bounds__(512, 2) void k_scan(
    const float* __restrict__ wq, const float* __restrict__ eaq,
    const float* __restrict__ Mv0, float* __restrict__ reads)
{
    __shared__ float pbuf[2][8][8][64];   // 32 KB

    const int tid = threadIdx.x;
    const int b = blockIdx.x >> 1;
    const int dh = blockIdx.x & 1;
    const int wv = tid >> 6;                                   // 0..7
    const int sc = __builtin_amdgcn_readfirstlane(wv);         // uniform wave id
    const int lane = tid & 63;
    const int d = dh * 64 + lane;

    float Mv[8];
    #pragma unroll
    for (int j = 0; j < 8; j++) Mv[j] = Mv0[(sc * 8 + j) * D_ + d];

    const float4* wb4 = (const float4*)(wq + b * (L_ * M_));
    const float2* eab = (const float2*)eaq + b * (L_ * 128) + d;
    float* rbase = reads + b * (L_ * D_) + dh * 64;

    float4 wA[16], wB[16];
    float2 eA[8], eB[8];

    SC_PREFETCH(wA, eA, 0);

    for (int cc = 0; cc < 12; cc++) {
        const int c0 = 2 * cc;
        SC_PREFETCH(wB, eB, c0 + 1);
        SC_COMPUTE(wA, eA, 0);
        __syncthreads();
        SC_REDUCE(0, c0);
        SC_PREFETCH(wA, eA, c0 + 2);
        SC_COMPUTE(wB, eB, 1);
        __syncthreads();
        SC_REDUCE(1, c0 + 1);
    }
    SC_COMPUTE(wA, eA, 0);
    __syncthreads();
    SC_REDUCE(0, 24);
}

// ---------- K3: MFMA f-GEMM + fused ab/out epilogue (8 waves) ----------
__global__ __launch_bounds__(512) void k_final_mfma(
    const float* __restrict__ reads, const float* __restrict__ fkq,
    const float* __restrict__ diffq, const ushort_t* __restrict__ Fpack,
    const float* __restrict__ f_b, const float* __restrict__ ab_W,
    const float* __restrict__ ab_b, float* __restrict__ out)
{
    __shared__ ushort_t srA[8192];
    __shared__ float sab[64 * 2];

    const int tid = threadIdx.x;
    const int pos0 = blockIdx.x * 64;
    const int wave = tid >> 6;
    const int lane = tid & 63;
    const int mt = wave & 3;        // m-tile
    const int half = wave >> 2;     // nt half

    #pragma unroll
    for (int i = 0; i < 2; i++) {
        int E = tid + 512 * i;
        int mtile = E >> 8, ks = (E >> 6) & 3, le = E & 63;
        int prow = pos0 + mtile * 16 + (le & 15);
        int dof = ks * 32 + ((le >> 4) << 3);
        const float4* rp = (const float4*)(reads + prow * 128 + dof);
        *(uint4*)&srA[E * 8] = pack8(rp[0], rp[1]);
    }

    const int col = lane & 15;
    const int quad = lane >> 4;
    const int rbase = mt * 16 + quad * 4;

    // hoisted fkq prefetch: 16 independent loads in flight at once
    float fkv[16];
    #pragma unroll
    for (int i = 0; i < 4; i++)
        #pragma unroll
        for (int reg = 0; reg < 4; reg++)
            fkv[i * 4 + reg] = fkq[(pos0 + rbase + reg) * 128 + (half * 4 + i) * 16 + col];

    __syncthreads();

    bf16x8 A[4];
    #pragma unroll
    for (int ks = 0; ks < 4; ks++)
        A[ks] = *(const bf16x8*)&srA[((mt * 4 + ks) * 64 + lane) * 8];

    float abacc[4] = {0.f, 0.f, 0.f, 0.f};

    bf16x8 Bb[2][4];
    loadB4(Fpack, half * 4, lane, Bb[0]);
    #pragma unroll
    for (int i = 0; i < 4; i++) {
        if (i < 3) loadB4(Fpack, half * 4 + i + 1, lane, Bb[(i + 1) & 1]);
        f32x4 acc = {0.f, 0.f, 0.f, 0.f};
        #pragma unroll
        for (int ks = 0; ks < 4; ks++)
            acc = __builtin_amdgcn_mfma_f32_16x16x32_bf16(A[ks], Bb[i & 1][ks], acc, 0, 0, 0);
        int c = (half * 4 + i) * 16 + col;
        float fb = f_b[c];
        float abw = ab_W[c];
        #pragma unroll
        for (int reg = 0; reg < 4; reg++) {
            float fv = fast_tanh(acc[reg] + fkv[i * 4 + reg] + fb);
            abacc[reg] = fmaf(abw, fv, abacc[reg]);
        }
    }

    #pragma unroll
    for (int reg = 0; reg < 4; reg++) {
        float v = abacc[reg];
        v += __shfl_xor(v, 1); v += __shfl_xor(v, 2);
        v += __shfl_xor(v, 4); v += __shfl_xor(v, 8);
        abacc[reg] = v;
    }
    if (col == 0) {
        #pragma unroll
        for (int reg = 0; reg < 4; reg++)
            sab[(rbase + reg) * 2 + half] = abacc[reg];
    }
    __syncthreads();
    if (tid < 64) {
        float ab = fast_tanh(sab[tid * 2] + sab[tid * 2 + 1] + ab_b[0]);
        int pos = pos0 + tid;
        out[pos] = fast_sigmoid(3.f * ab - diffq[pos]);
    }
}

// ---------- launch ----------
extern "C" void kernel_launch(void* const* d_in, const int* in_sizes, int n_in,
                              void* d_out, int out_size, void* d_ws, size_t ws_size,
                              hipStream_t stream)
{
    const int*   q     = (const int*)d_in[0];
    const int*   r     = (const int*)d_in[1];
    const float* k_emb = (const float*)d_in[2];
    const float* v_emb = (const float*)d_in[3];
    const float* Mk    = (const float*)d_in[4];
    const float* Mv0   = (const float*)d_in[5];
    const float* f_W   = (const float*)d_in[6];
    const float* f_b   = (const float*)d_in[7];
    const float* e_W   = (const float*)d_in[8];
    const float* e_b   = (const float*)d_in[9];
    const float* a_W   = (const float*)d_in[10];
    const float* a_b   = (const float*)d_in[11];
    const float* ab_W  = (const float*)d_in[12];
    const float* ab_b  = (const float*)d_in[13];
    const float* df_W  = (const float*)d_in[14];
    const float* df_b  = (const float*)d_in[15];

    float* ws = (float*)d_ws;
    float* out = (float*)d_out;
    ushort_t* Wpack = (ushort_t*)(ws + F_PACK);
    ushort_t* Fpack = Wpack + WPACK_N;

    // K0: pack weights to bf16 fragment layout
    k_pack<<<288, 256, 0, stream>>>(Mk, e_W, a_W, f_W, Wpack, Fpack);

    // K1: unified MFMA projections + softmax + diff (400 blocks x 8 waves)
    k_pre_mfma<<<400, 512, 0, stream>>>(
        q, r, k_emb, v_emb, Wpack, e_b, a_b, df_W, df_b,
        ws + F_WQ, ws + F_EAQ, ws + F_FKQ, ws + F_DIFF);

    // K2: scan (128 b x 2 d-halves, 8 waves, chunk-prefetched)
    k_scan<<<256, 512, 0, stream>>>(
        ws + F_WQ, ws + F_EAQ, Mv0, ws + F_RD);

    // K3: final MFMA + epilogue (400 blocks x 8 waves)
    k_final_mfma<<<400, 512, 0, stream>>>(
        ws + F_RD, ws + F_FKQ, ws + F_DIFF, Fpack,
        f_b, ab_W, ab_b, out);
}